// Round 1
// baseline (191.780 us; speedup 1.0000x reference)
//
#include <hip/hip_runtime.h>

// ---------------------------------------------------------------------------
// FlashAttention_45844480917693 — cosine-sim attention, MI355X (gfx950)
// Pipeline: convert x->fp16, transpose weights, fused QKV GEMM (+l2norm),
// flash attention (no-max exp accumulation: logits <= 0 by construction),
// output GEMM. All matmuls via v_mfma_f32_16x16x32_f16, fp32 accumulation.
// ---------------------------------------------------------------------------

typedef _Float16 f16;
typedef _Float16 f16x8 __attribute__((ext_vector_type(8)));
typedef float f32x4 __attribute__((ext_vector_type(4)));

#define MFMA_F16(a, b, c) __builtin_amdgcn_mfma_f32_16x16x32_f16((a), (b), (c), 0, 0, 0)

__device__ __forceinline__ void gl_lds16(const void* g, void* l) {
  // async global->LDS, 16B per lane; LDS dest must be wave-uniform base + lane*16
  __builtin_amdgcn_global_load_lds(
      (const __attribute__((address_space(1))) void*)g,
      (__attribute__((address_space(3))) void*)l, 16, 0, 0);
}

// ---------------------------------------------------------------------------
// x (fp32) -> fp16, 8 elements/thread
__global__ void convert_x_kernel(const float* __restrict__ x, f16* __restrict__ xh, int n8) {
  int i = blockIdx.x * 256 + threadIdx.x;
  if (i >= n8) return;
  const float4* xv = (const float4*)x;
  float4 a = xv[2 * i], b = xv[2 * i + 1];
  f16x8 o;
  o[0] = (f16)a.x; o[1] = (f16)a.y; o[2] = (f16)a.z; o[3] = (f16)a.w;
  o[4] = (f16)b.x; o[5] = (f16)b.y; o[6] = (f16)b.z; o[7] = (f16)b.w;
  ((f16x8*)xh)[i] = o;
}

// W [K][ldw] fp32, take cols [col0, col0+gridDim.x*64) -> out[c][k] fp16 ([out][in])
__global__ void transpose_w_kernel(const float* __restrict__ W, int ldw, int col0,
                                   int K, f16* __restrict__ out) {
  __shared__ float t[64][65];
  int tx = threadIdx.x, ty = threadIdx.y;
  int c0 = blockIdx.x * 64, k0 = blockIdx.y * 64;
#pragma unroll
  for (int i = 0; i < 8; i++)
    t[ty + i * 8][tx] = W[(long)(k0 + ty + i * 8) * ldw + col0 + c0 + tx];
  __syncthreads();
#pragma unroll
  for (int i = 0; i < 8; i++)
    out[(long)(c0 + ty + i * 8) * K + k0 + tx] = (f16)t[tx][ty + i * 8];
}

// ---------------------------------------------------------------------------
// GEMM: C[M][N] = A[M][K] * Bt[N][K]^T, 128x128 tile, BK=32, 4 waves (2x2),
// each wave 64x64 as 4x4 16x16 frags. MODE 0: fp32 C out. MODE 1: fused QKV
// epilogue: per-row l2norm over each head (64 cols) for Q/K, scatter fp16 to
// [b*8+h][n][64] buffers.
template <int MODE>
__global__ __launch_bounds__(256, 2)
void gemm_kernel(const f16* __restrict__ A, const f16* __restrict__ Bt,
                 float* __restrict__ C,
                 f16* __restrict__ Qb, f16* __restrict__ Kb, f16* __restrict__ Vb,
                 int M, int N, int K) {
  __shared__ f16 As[128 * 32];
  __shared__ f16 Bs[128 * 32];
  const int tid = threadIdx.x;
  const int lane = tid & 63;
  const int wid = tid >> 6;
  const int wr = wid >> 1, wc = wid & 1;
  const int lr = lane & 15, lk = lane >> 4;
  const long m0 = (long)blockIdx.x * 128;
  const int n0 = blockIdx.y * 128;

  f32x4 acc[4][4] = {};

  // staging: 512 x 16B chunks per 128x32 tile; chunk c: row=c>>2, pos=c&3.
  // source chunk pre-swizzled (ch ^ ((row>>1)&3)) so LDS stays lane-linear.
  const int c0 = tid, c1 = tid + 256;
  const int ar0 = c0 >> 2, ah0 = (c0 & 3) ^ ((ar0 >> 1) & 3);
  const int ar1 = c1 >> 2, ah1 = (c1 & 3) ^ ((ar1 >> 1) & 3);
  const f16* pa0 = A + (m0 + ar0) * K + ah0 * 8;
  const f16* pa1 = A + (m0 + ar1) * K + ah1 * 8;
  const f16* pb0 = Bt + (long)(n0 + ar0) * K + ah0 * 8;
  const f16* pb1 = Bt + (long)(n0 + ar1) * K + ah1 * 8;

  for (int k0 = 0; k0 < K; k0 += 32) {
    __syncthreads();  // previous tile fully consumed
    gl_lds16(pa0 + k0, As + c0 * 8);
    gl_lds16(pa1 + k0, As + c1 * 8);
    gl_lds16(pb0 + k0, Bs + c0 * 8);
    gl_lds16(pb1 + k0, Bs + c1 * 8);
    __syncthreads();  // staging complete (barrier drains vmcnt)

    f16x8 af[4], bf[4];
#pragma unroll
    for (int mi = 0; mi < 4; mi++) {
      int row = wr * 64 + mi * 16 + lr;
      int ch = lk ^ ((row >> 1) & 3);
      af[mi] = *(const f16x8*)(As + row * 32 + ch * 8);
    }
#pragma unroll
    for (int ni = 0; ni < 4; ni++) {
      int row = wc * 64 + ni * 16 + lr;
      int ch = lk ^ ((row >> 1) & 3);
      bf[ni] = *(const f16x8*)(Bs + row * 32 + ch * 8);
    }
#pragma unroll
    for (int mi = 0; mi < 4; mi++)
#pragma unroll
      for (int ni = 0; ni < 4; ni++)
        acc[mi][ni] = MFMA_F16(af[mi], bf[ni], acc[mi][ni]);
  }

  // D frag layout (verified m89): col = lane&15, row = (lane>>4)*4 + reg
  if (MODE == 0) {
#pragma unroll
    for (int mi = 0; mi < 4; mi++) {
      long mrow = m0 + wr * 64 + mi * 16 + lk * 4;
#pragma unroll
      for (int r = 0; r < 4; r++)
#pragma unroll
        for (int ni = 0; ni < 4; ni++)
          C[(mrow + r) * N + n0 + wc * 64 + ni * 16 + lr] = acc[mi][ni][r];
    }
  } else {
    const int region = blockIdx.y >> 2;              // 0=Q, 1=K, 2=V
    const int head = (blockIdx.y & 3) * 2 + wc;      // wave's 64 cols = one head
    f16* buf = (region == 0) ? Qb : ((region == 1) ? Kb : Vb);
#pragma unroll
    for (int mi = 0; mi < 4; mi++) {
      float scl[4];
      if (region < 2) {
#pragma unroll
        for (int r = 0; r < 4; r++) {
          float s2 = 0.f;
#pragma unroll
          for (int ni = 0; ni < 4; ni++) s2 += acc[mi][ni][r] * acc[mi][ni][r];
          s2 += __shfl_xor(s2, 1);
          s2 += __shfl_xor(s2, 2);
          s2 += __shfl_xor(s2, 4);
          s2 += __shfl_xor(s2, 8);   // row sum-of-squares over 64 cols
          scl[r] = 1.f / fmaxf(sqrtf(s2), 1e-12f);
        }
      } else {
#pragma unroll
        for (int r = 0; r < 4; r++) scl[r] = 1.f;
      }
#pragma unroll
      for (int r = 0; r < 4; r++) {
        int m = (int)m0 + wr * 64 + mi * 16 + lk * 4 + r;
        int bb = m >> 12, nn = m & 4095;
        f16* dst = buf + (((long)(bb * 8 + head) * 4096 + nn) << 6);
#pragma unroll
        for (int ni = 0; ni < 4; ni++)
          dst[ni * 16 + lr] = (f16)(acc[mi][ni][r] * scl[r]);
      }
    }
  }
}

// ---------------------------------------------------------------------------
// Attention: grid (n/128, b*h). Block = 4 waves; wave owns 32 q-rows.
// Per 64-key tile: S = Q*K^T (fp16 MFMA), p = exp2(16*log2e*(s-1)) (<=~1, no
// max tracking needed), accumulate rowsum, P->LDS (fp16), O += P*V.
// All LDS tiles XOR-swizzled: [x][64]-f16 rows are 128B -> 16-way conflict
// without swizzle.
__global__ __launch_bounds__(256, 2)
void attn_kernel(const f16* __restrict__ Qb, const f16* __restrict__ Kb,
                 const f16* __restrict__ Vb, f16* __restrict__ Ob, int n) {
  __shared__ f16 Ks[64 * 64];        // [j][d], chunk ^= (j&7)
  __shared__ f16 Vs[64 * 64];        // [d][j] (transposed), chunk ^= (d&7)
  __shared__ f16 Ps[4][32 * 64];     // per-wave [q][j], chunk ^= ((q>>1)&7)
  const int tid = threadIdx.x, lane = tid & 63, wid = tid >> 6;
  const int lr = lane & 15, lk = lane >> 4;
  const int bh = blockIdx.y;
  const long base = (long)bh * n * 64;
  const f16* Qg = Qb + base;
  const f16* Kg = Kb + base;
  const f16* Vg = Vb + base;
  const int q0 = blockIdx.x * 128 + wid * 32;

  // Q fragments live in registers for the whole kernel
  f16x8 qf[2][2];
#pragma unroll
  for (int mi = 0; mi < 2; mi++)
#pragma unroll
    for (int kc = 0; kc < 2; kc++)
      qf[mi][kc] = *(const f16x8*)(Qg + (long)(q0 + mi * 16 + lr) * 64 + kc * 32 + lk * 8);

  f32x4 oacc[2][4] = {};
  float rsum[2][4] = {};

  const int c0 = tid, c1 = tid + 256;
  const int kr0 = c0 >> 3, kh0 = (c0 & 7) ^ (kr0 & 7);
  const int kr1 = c1 >> 3, kh1 = (c1 & 7) ^ (kr1 & 7);
  const int vj = tid & 63, vd0 = (tid >> 6) * 16;

  for (int j0 = 0; j0 < n; j0 += 64) {
    __syncthreads();  // everyone done with previous K/V tiles
    gl_lds16(Kg + (long)(j0 + kr0) * 64 + kh0 * 8, Ks + c0 * 8);
    gl_lds16(Kg + (long)(j0 + kr1) * 64 + kh1 * 8, Ks + c1 * 8);
    // V: register-stage and write transposed (+swizzled) into LDS
    f16x8 v0 = *(const f16x8*)(Vg + (long)(j0 + vj) * 64 + vd0);
    f16x8 v1 = *(const f16x8*)(Vg + (long)(j0 + vj) * 64 + vd0 + 8);
#pragma unroll
    for (int e = 0; e < 8; e++) {
      int d = vd0 + e;
      Vs[d * 64 + ((((vj >> 3) ^ (d & 7)) << 3) | (vj & 7))] = v0[e];
      d += 8;
      Vs[d * 64 + ((((vj >> 3) ^ (d & 7)) << 3) | (vj & 7))] = v1[e];
    }
    __syncthreads();  // staging visible (barrier drains vmcnt+lgkmcnt)

    // S = Q*K^T : A=Q rows(queries), B=K^T (K rows as B cols)
    f32x4 s[2][4] = {};
#pragma unroll
    for (int kc = 0; kc < 2; kc++)
#pragma unroll
      for (int nt = 0; nt < 4; nt++) {
        int j = nt * 16 + lr;
        int ch = (kc * 4 + lk) ^ (j & 7);
        f16x8 kf = *(const f16x8*)(Ks + j * 64 + ch * 8);
        s[0][nt] = MFMA_F16(qf[0][kc], kf, s[0][nt]);
        s[1][nt] = MFMA_F16(qf[1][kc], kf, s[1][nt]);
      }

    // p = exp(16*s - 16) = 2^(16*log2e*(s-1)); accumulate rowsum; P -> LDS fp16
#pragma unroll
    for (int mi = 0; mi < 2; mi++)
#pragma unroll
      for (int nt = 0; nt < 4; nt++)
#pragma unroll
        for (int r = 0; r < 4; r++) {
          float p = __builtin_amdgcn_exp2f(
              fmaf(s[mi][nt][r], 23.083120654223414f, -23.083120654223414f));
          rsum[mi][r] += p;
          int q = mi * 16 + lk * 4 + r;
          int j = nt * 16 + lr;
          int ch = (j >> 3) ^ ((q >> 1) & 7);
          Ps[wid][q * 64 + (ch << 3) + (j & 7)] = (f16)p;
        }

    // O += P * V : A=P (per-wave LDS), B=V^T (Vs)
#pragma unroll
    for (int kc = 0; kc < 2; kc++) {
      f16x8 pa[2], vf[4];
#pragma unroll
      for (int mi = 0; mi < 2; mi++) {
        int q = mi * 16 + lr;
        int ch = (kc * 4 + lk) ^ ((q >> 1) & 7);
        pa[mi] = *(const f16x8*)(&Ps[wid][q * 64 + ch * 8]);
      }
#pragma unroll
      for (int dt = 0; dt < 4; dt++) {
        int d = dt * 16 + lr;
        int ch = (kc * 4 + lk) ^ (d & 7);
        vf[dt] = *(const f16x8*)(Vs + d * 64 + ch * 8);
      }
#pragma unroll
      for (int mi = 0; mi < 2; mi++)
#pragma unroll
        for (int dt = 0; dt < 4; dt++)
          oacc[mi][dt] = MFMA_F16(pa[mi], vf[dt], oacc[mi][dt]);
    }
  }

  // finalize: rowsum reduce over 16 key-lanes, divide, store [b,n,h*64+d] fp16
  const int bb = bh >> 3, hh = bh & 7;
#pragma unroll
  for (int mi = 0; mi < 2; mi++)
#pragma unroll
    for (int r = 0; r < 4; r++) {
      float t = rsum[mi][r];
      t += __shfl_xor(t, 1);
      t += __shfl_xor(t, 2);
      t += __shfl_xor(t, 4);
      t += __shfl_xor(t, 8);
      float inv = 1.f / fmaxf(t, 1e-6f);
      int qq = q0 + mi * 16 + lk * 4 + r;
      f16* dst = Ob + (((long)(bb * 4096 + qq)) << 9) + hh * 64;
#pragma unroll
      for (int dt = 0; dt < 4; dt++)
        dst[dt * 16 + lr] = (f16)(oacc[mi][dt][r] * inv);
    }
}

// ---------------------------------------------------------------------------
extern "C" void kernel_launch(void* const* d_in, const int* in_sizes, int n_in,
                              void* d_out, int out_size, void* d_ws, size_t ws_size,
                              hipStream_t stream) {
  const float* x   = (const float*)d_in[0];   // [2,4096,1024]
  const float* Wq  = (const float*)d_in[1];   // [1024,512]
  const float* Wkv = (const float*)d_in[2];   // [1024,1024]
  const float* Wo  = (const float*)d_in[3];   // [512,1024]
  float* out = (float*)d_out;                 // [2,4096,1024] fp32

  char* ws = (char*)d_ws;
  f16* xh     = (f16*)(ws);                   // 16.78 MB  [8192][1024]
  f16* Wqkv_t = (f16*)(ws + 16777216);        //  3.15 MB  [1536][1024]  (q|k|v)^T
  f16* Wo_t   = (f16*)(ws + 19922944);        //  1.05 MB  [1024][512]
  f16* Qb     = (f16*)(ws + 20971520);        //  8.39 MB  [16][4096][64]
  f16* Kb     = (f16*)(ws + 29360128);        //  8.39 MB
  f16* Vb     = (f16*)(ws + 37748736);        //  8.39 MB
  f16* At     = (f16*)(ws + 46137344);        //  8.39 MB  [8192][512]
  // total 54.5 MB

  convert_x_kernel<<<4096, 256, 0, stream>>>(x, xh, 1048576);

  dim3 tb(64, 8);
  transpose_w_kernel<<<dim3(8, 16), tb, 0, stream>>>(Wq, 512, 0, 1024, Wqkv_t);
  transpose_w_kernel<<<dim3(8, 16), tb, 0, stream>>>(Wkv, 1024, 0, 1024, Wqkv_t + 512 * 1024);
  transpose_w_kernel<<<dim3(8, 16), tb, 0, stream>>>(Wkv, 1024, 512, 1024, Wqkv_t + 1024 * 1024);
  transpose_w_kernel<<<dim3(16, 8), tb, 0, stream>>>(Wo, 1024, 0, 512, Wo_t);

  // fused QKV projection + l2norm: [8192 x 1536 x 1024]
  gemm_kernel<1><<<dim3(64, 12), 256, 0, stream>>>(xh, Wqkv_t, nullptr, Qb, Kb, Vb,
                                                   8192, 1536, 1024);
  // attention
  attn_kernel<<<dim3(32, 16), 256, 0, stream>>>(Qb, Kb, Vb, At, 4096);
  // output projection: [8192 x 1024 x 512]
  gemm_kernel<0><<<dim3(64, 8), 256, 0, stream>>>(At, Wo_t, out, nullptr, nullptr, nullptr,
                                                  8192, 1024, 512);
}

// Round 2
// 173.862 us; speedup vs baseline: 1.1031x; 1.1031x over previous
//
#include <hip/hip_runtime.h>

// ---------------------------------------------------------------------------
// FlashAttention_45844480917693 — cosine-sim attention, MI355X (gfx950)
// R2: attn rewritten — swapped QK^T (rows=j, cols=q), packed P (cvt_pkrtz +
// ds_write_b64), pre-transposed V (separate kernel), double-buffered K/V with
// prefetch-before-compute (one barrier per tile). fp16 MFMA, fp32 accum.
// ---------------------------------------------------------------------------

typedef _Float16 f16;
typedef _Float16 f16x4 __attribute__((ext_vector_type(4)));
typedef _Float16 f16x8 __attribute__((ext_vector_type(8)));
typedef float f32x4 __attribute__((ext_vector_type(4)));

#define MFMA_F16(a, b, c) __builtin_amdgcn_mfma_f32_16x16x32_f16((a), (b), (c), 0, 0, 0)

__device__ __forceinline__ void gl_lds16(const void* g, void* l) {
  // async global->LDS, 16B per lane; LDS dest = wave-uniform base + lane*16
  __builtin_amdgcn_global_load_lds(
      (const __attribute__((address_space(1))) void*)g,
      (__attribute__((address_space(3))) void*)l, 16, 0, 0);
}

// ---------------------------------------------------------------------------
// x (fp32) -> fp16, 8 elements/thread
__global__ void convert_x_kernel(const float* __restrict__ x, f16* __restrict__ xh, int n8) {
  int i = blockIdx.x * 256 + threadIdx.x;
  if (i >= n8) return;
  const float4* xv = (const float4*)x;
  float4 a = xv[2 * i], b = xv[2 * i + 1];
  f16x8 o;
  o[0] = (f16)a.x; o[1] = (f16)a.y; o[2] = (f16)a.z; o[3] = (f16)a.w;
  o[4] = (f16)b.x; o[5] = (f16)b.y; o[6] = (f16)b.z; o[7] = (f16)b.w;
  ((f16x8*)xh)[i] = o;
}

// W [K][ldw] fp32, take cols [col0, col0+gridDim.x*64) -> out[c][k] fp16 ([out][in])
__global__ void transpose_w_kernel(const float* __restrict__ W, int ldw, int col0,
                                   int K, f16* __restrict__ out) {
  __shared__ float t[64][65];
  int tx = threadIdx.x, ty = threadIdx.y;
  int c0 = blockIdx.x * 64, k0 = blockIdx.y * 64;
#pragma unroll
  for (int i = 0; i < 8; i++)
    t[ty + i * 8][tx] = W[(long)(k0 + ty + i * 8) * ldw + col0 + c0 + tx];
  __syncthreads();
#pragma unroll
  for (int i = 0; i < 8; i++)
    out[(long)(c0 + ty + i * 8) * K + k0 + tx] = (f16)t[tx][ty + i * 8];
}

// Vb [bh][n][64] -> Vt [bh][64][n], 64x64 f16 tiles, swizzled LDS
__global__ void transpose_v_kernel(const f16* __restrict__ Vb, f16* __restrict__ Vt, int n) {
  __shared__ f16 t[64 * 64];
  const int tid = threadIdx.x;
  const int bh = blockIdx.y;
  const int n0 = blockIdx.x * 64;
  const f16* src = Vb + ((long)bh * n + n0) * 64;
  const int j = tid >> 3, c = tid & 7;
  f16x8 v0 = *(const f16x8*)(src + j * 64 + c * 8);
  f16x8 v1 = *(const f16x8*)(src + (j + 32) * 64 + c * 8);
  *(f16x8*)(&t[j * 64 + ((c ^ (j & 7)) << 3)]) = v0;
  *(f16x8*)(&t[(j + 32) * 64 + ((c ^ (j & 7)) << 3)]) = v1;  // (j+32)&7 == j&7
  __syncthreads();
  const int d = tid >> 3, cj = tid & 7;
  f16x8 o0, o1;
#pragma unroll
  for (int e = 0; e < 8; e++) {
    int jj = cj * 8 + e;
    o0[e] = t[jj * 64 + (((d >> 3) ^ (jj & 7)) << 3) + (d & 7)];
    o1[e] = t[jj * 64 + ((((d + 32) >> 3) ^ (jj & 7)) << 3) + ((d + 32) & 7)];
  }
  *(f16x8*)(Vt + ((long)bh * 64 + d) * n + n0 + cj * 8) = o0;
  *(f16x8*)(Vt + ((long)bh * 64 + d + 32) * n + n0 + cj * 8) = o1;
}

// ---------------------------------------------------------------------------
// GEMM: C[M][N] = A[M][K] * Bt[N][K]^T, 128x128 tile, BK=32, 4 waves (2x2),
// MODE 0: fp32 C out. MODE 1: fused QKV epilogue (l2norm for Q/K).
template <int MODE>
__global__ __launch_bounds__(256, 2)
void gemm_kernel(const f16* __restrict__ A, const f16* __restrict__ Bt,
                 float* __restrict__ C,
                 f16* __restrict__ Qb, f16* __restrict__ Kb, f16* __restrict__ Vb,
                 int M, int N, int K) {
  __shared__ f16 As[128 * 32];
  __shared__ f16 Bs[128 * 32];
  const int tid = threadIdx.x;
  const int lane = tid & 63;
  const int wid = tid >> 6;
  const int wr = wid >> 1, wc = wid & 1;
  const int lr = lane & 15, lk = lane >> 4;
  const long m0 = (long)blockIdx.x * 128;
  const int n0 = blockIdx.y * 128;

  f32x4 acc[4][4] = {};

  const int c0 = tid, c1 = tid + 256;
  const int ar0 = c0 >> 2, ah0 = (c0 & 3) ^ ((ar0 >> 1) & 3);
  const int ar1 = c1 >> 2, ah1 = (c1 & 3) ^ ((ar1 >> 1) & 3);
  const f16* pa0 = A + (m0 + ar0) * K + ah0 * 8;
  const f16* pa1 = A + (m0 + ar1) * K + ah1 * 8;
  const f16* pb0 = Bt + (long)(n0 + ar0) * K + ah0 * 8;
  const f16* pb1 = Bt + (long)(n0 + ar1) * K + ah1 * 8;

  for (int k0 = 0; k0 < K; k0 += 32) {
    __syncthreads();
    gl_lds16(pa0 + k0, As + c0 * 8);
    gl_lds16(pa1 + k0, As + c1 * 8);
    gl_lds16(pb0 + k0, Bs + c0 * 8);
    gl_lds16(pb1 + k0, Bs + c1 * 8);
    __syncthreads();

    f16x8 af[4], bf[4];
#pragma unroll
    for (int mi = 0; mi < 4; mi++) {
      int row = wr * 64 + mi * 16 + lr;
      int ch = lk ^ ((row >> 1) & 3);
      af[mi] = *(const f16x8*)(As + row * 32 + ch * 8);
    }
#pragma unroll
    for (int ni = 0; ni < 4; ni++) {
      int row = wc * 64 + ni * 16 + lr;
      int ch = lk ^ ((row >> 1) & 3);
      bf[ni] = *(const f16x8*)(Bs + row * 32 + ch * 8);
    }
#pragma unroll
    for (int mi = 0; mi < 4; mi++)
#pragma unroll
      for (int ni = 0; ni < 4; ni++)
        acc[mi][ni] = MFMA_F16(af[mi], bf[ni], acc[mi][ni]);
  }

  if (MODE == 0) {
#pragma unroll
    for (int mi = 0; mi < 4; mi++) {
      long mrow = m0 + wr * 64 + mi * 16 + lk * 4;
#pragma unroll
      for (int r = 0; r < 4; r++)
#pragma unroll
        for (int ni = 0; ni < 4; ni++)
          C[(mrow + r) * N + n0 + wc * 64 + ni * 16 + lr] = acc[mi][ni][r];
    }
  } else {
    const int region = blockIdx.y >> 2;              // 0=Q, 1=K, 2=V
    const int head = (blockIdx.y & 3) * 2 + wc;
    f16* buf = (region == 0) ? Qb : ((region == 1) ? Kb : Vb);
#pragma unroll
    for (int mi = 0; mi < 4; mi++) {
      float scl[4];
      if (region < 2) {
#pragma unroll
        for (int r = 0; r < 4; r++) {
          float s2 = 0.f;
#pragma unroll
          for (int ni = 0; ni < 4; ni++) s2 += acc[mi][ni][r] * acc[mi][ni][r];
          s2 += __shfl_xor(s2, 1);
          s2 += __shfl_xor(s2, 2);
          s2 += __shfl_xor(s2, 4);
          s2 += __shfl_xor(s2, 8);
          scl[r] = 1.f / fmaxf(sqrtf(s2), 1e-12f);
        }
      } else {
#pragma unroll
        for (int r = 0; r < 4; r++) scl[r] = 1.f;
      }
#pragma unroll
      for (int r = 0; r < 4; r++) {
        int m = (int)m0 + wr * 64 + mi * 16 + lk * 4 + r;
        int bb = m >> 12, nn = m & 4095;
        f16* dst = buf + (((long)(bb * 8 + head) * 4096 + nn) << 6);
#pragma unroll
        for (int ni = 0; ni < 4; ni++)
          dst[ni * 16 + lr] = (f16)(acc[mi][ni][r] * scl[r]);
      }
    }
  }
}

// ---------------------------------------------------------------------------
// Attention v2. grid (n/128, b*h), 4 waves x 32 q-rows. Double-buffered K/V
// (prefetch issued before compute, one barrier/tile). Swapped QK^T: rows=j,
// cols=q -> P j-consecutive per lane -> pk-convert + b64 writes. V comes
// pre-transposed (Vt [bh][64][n]) so staging is pure global_load_lds.
// P scaled by 2^14 (cancels in rowsum division) to sit in f16 normal range.
__global__ __launch_bounds__(256, 2)
void attn_kernel(const f16* __restrict__ Qb, const f16* __restrict__ Kb,
                 const f16* __restrict__ Vt, f16* __restrict__ Ob, int n) {
  __shared__ f16 Ks[2][64 * 64];     // [j][d], chunk ^= (j&7)
  __shared__ f16 Vs[2][64 * 64];     // [d][j], chunk ^= (d&7)
  __shared__ f16 Ps[4][32 * 64];     // per-wave [q][j], 16B-chunk ^= (q&7)
  const int tid = threadIdx.x, lane = tid & 63, wid = tid >> 6;
  const int lr = lane & 15, lk = lane >> 4;
  const int bh = blockIdx.y;
  const long nl = n;
  const f16* Qg = Qb + (long)bh * nl * 64;
  const f16* Kg = Kb + (long)bh * nl * 64;
  const f16* Vg = Vt + (long)bh * 64 * nl;
  const int q0 = blockIdx.x * 128 + wid * 32;

  // Q fragments (B-operand of swapped QK^T): col q = lr, k d = kc*32+lk*8+e
  f16x8 qf[2][2];
#pragma unroll
  for (int qt = 0; qt < 2; qt++)
#pragma unroll
    for (int kc = 0; kc < 2; kc++)
      qf[qt][kc] = *(const f16x8*)(Qg + (long)(q0 + qt * 16 + lr) * 64 + kc * 32 + lk * 8);

  const int sr = tid >> 3;              // staging row (0..31; +32 for 2nd half)
  const int sc = (tid & 7) ^ (sr & 7);  // pre-swizzled source chunk

  f32x4 oacc[2][4] = {};
  float rsum[2] = {0.f, 0.f};

  // prologue: stage tile 0 into buf 0
  gl_lds16(Kg + (long)sr * 64 + sc * 8, &Ks[0][tid * 8]);
  gl_lds16(Kg + (long)(sr + 32) * 64 + sc * 8, &Ks[0][tid * 8 + 2048]);
  gl_lds16(Vg + (long)sr * nl + sc * 8, &Vs[0][tid * 8]);
  gl_lds16(Vg + (long)(sr + 32) * nl + sc * 8, &Vs[0][tid * 8 + 2048]);
  __syncthreads();

  const int nt = n >> 6;
  for (int t = 0; t < nt; t++) {
    const int cur = t & 1;
    // prefetch tile t+1 into the other buffer — overlaps ALL of compute(t)
    if (t + 1 < nt) {
      const long j0 = (long)(t + 1) << 6;
      gl_lds16(Kg + (j0 + sr) * 64 + sc * 8, &Ks[cur ^ 1][tid * 8]);
      gl_lds16(Kg + (j0 + sr + 32) * 64 + sc * 8, &Ks[cur ^ 1][tid * 8 + 2048]);
      gl_lds16(Vg + (long)sr * nl + j0 + sc * 8, &Vs[cur ^ 1][tid * 8]);
      gl_lds16(Vg + (long)(sr + 32) * nl + j0 + sc * 8, &Vs[cur ^ 1][tid * 8 + 2048]);
    }

    // S^T = K * Q^T : rows j (regs), cols q (lanes)
    f32x4 s0[4] = {}, s1[4] = {};
#pragma unroll
    for (int kc = 0; kc < 2; kc++)
#pragma unroll
      for (int jt = 0; jt < 4; jt++) {
        const int j = jt * 16 + lr;
        const f16x8 kf =
            *(const f16x8*)(&Ks[cur][j * 64 + (((kc * 4 + lk) ^ (j & 7)) << 3)]);
        s0[jt] = MFMA_F16(kf, qf[0][kc], s0[jt]);
        s1[jt] = MFMA_F16(kf, qf[1][kc], s1[jt]);
      }

    // p' = 2^(16*log2e*(s-1) + 14); rowsum; pack 4 f16 -> one b64 LDS write
#pragma unroll
    for (int jt = 0; jt < 4; jt++)
#pragma unroll
      for (int qt = 0; qt < 2; qt++) {
        const f32x4 sv = qt ? s1[jt] : s0[jt];
        const float p0 = __builtin_amdgcn_exp2f(fmaf(sv[0], 23.083120654223414f, -9.083120654223414f));
        const float p1 = __builtin_amdgcn_exp2f(fmaf(sv[1], 23.083120654223414f, -9.083120654223414f));
        const float p2 = __builtin_amdgcn_exp2f(fmaf(sv[2], 23.083120654223414f, -9.083120654223414f));
        const float p3 = __builtin_amdgcn_exp2f(fmaf(sv[3], 23.083120654223414f, -9.083120654223414f));
        rsum[qt] += (p0 + p1) + (p2 + p3);
        const auto h01 = __builtin_amdgcn_cvt_pkrtz(p0, p1);
        const auto h23 = __builtin_amdgcn_cvt_pkrtz(p2, p3);
        f16x4 pk;
        pk[0] = h01[0]; pk[1] = h01[1]; pk[2] = h23[0]; pk[3] = h23[1];
        const int q = qt * 16 + lr;
        const int c16 = jt * 2 + (lk >> 1);
        *(f16x4*)(&Ps[wid][q * 64 + ((c16 ^ (lr & 7)) << 3) + ((lk & 1) << 2)]) = pk;
      }

    // O += P * V : A = P (row q, k j), B = V^T rows (col d, k j)
#pragma unroll
    for (int kc = 0; kc < 2; kc++) {
      const int c16 = kc * 4 + lk;
      const f16x8 pa0 = *(const f16x8*)(&Ps[wid][lr * 64 + ((c16 ^ (lr & 7)) << 3)]);
      const f16x8 pa1 = *(const f16x8*)(&Ps[wid][(16 + lr) * 64 + ((c16 ^ (lr & 7)) << 3)]);
      f16x8 vf[4];
#pragma unroll
      for (int dt = 0; dt < 4; dt++) {
        const int d = dt * 16 + lr;
        vf[dt] = *(const f16x8*)(&Vs[cur][d * 64 + ((c16 ^ (d & 7)) << 3)]);
      }
#pragma unroll
      for (int dt = 0; dt < 4; dt++) {
        oacc[0][dt] = MFMA_F16(pa0, vf[dt], oacc[0][dt]);
        oacc[1][dt] = MFMA_F16(pa1, vf[dt], oacc[1][dt]);
      }
    }

    __syncthreads();  // drains prefetch vmcnt + all waves done with buf[cur]
  }

  // rowsum reduce over the 4 lk groups, redistribute to output layout, store
#pragma unroll
  for (int qt = 0; qt < 2; qt++) {
    float ts = rsum[qt];
    ts += __shfl_xor(ts, 16);
    ts += __shfl_xor(ts, 32);
    rsum[qt] = ts;
  }
  const int bb = bh >> 3, hh = bh & 7;
#pragma unroll
  for (int qt = 0; qt < 2; qt++)
#pragma unroll
    for (int r = 0; r < 4; r++) {
      const float sm = __shfl(rsum[qt], lk * 4 + r);       // sum for q-row lk*4+r
      const float inv = 1.f / fmaxf(sm, 0.016384f);        // 1e-6 * 2^14
      const int qq = q0 + qt * 16 + lk * 4 + r;
      f16* dst = Ob + (((long)(bb * 4096 + qq)) << 9) + hh * 64;
#pragma unroll
      for (int dt = 0; dt < 4; dt++)
        dst[dt * 16 + lr] = (f16)(oacc[qt][dt][r] * inv);
    }
}

// ---------------------------------------------------------------------------
extern "C" void kernel_launch(void* const* d_in, const int* in_sizes, int n_in,
                              void* d_out, int out_size, void* d_ws, size_t ws_size,
                              hipStream_t stream) {
  const float* x   = (const float*)d_in[0];   // [2,4096,1024]
  const float* Wq  = (const float*)d_in[1];   // [1024,512]
  const float* Wkv = (const float*)d_in[2];   // [1024,1024]
  const float* Wo  = (const float*)d_in[3];   // [512,1024]
  float* out = (float*)d_out;                 // [2,4096,1024] fp32

  char* ws = (char*)d_ws;
  f16* xh     = (f16*)(ws);                   // 16.78 MB  [8192][1024]; reused as Vt after QKV GEMM
  f16* Wqkv_t = (f16*)(ws + 16777216);        //  3.15 MB  [1536][1024]
  f16* Wo_t   = (f16*)(ws + 19922944);        //  1.05 MB  [1024][512]
  f16* Qb     = (f16*)(ws + 20971520);        //  8.39 MB  [16][4096][64]
  f16* Kb     = (f16*)(ws + 29360128);        //  8.39 MB
  f16* Vb     = (f16*)(ws + 37748736);        //  8.39 MB
  f16* At     = (f16*)(ws + 46137344);        //  8.39 MB  [8192][512]
  f16* Vt     = xh;                           //  8.39 MB  [16][64][4096] (xh dead after QKV GEMM)

  convert_x_kernel<<<4096, 256, 0, stream>>>(x, xh, 1048576);

  dim3 tb(64, 8);
  transpose_w_kernel<<<dim3(8, 16), tb, 0, stream>>>(Wq, 512, 0, 1024, Wqkv_t);
  transpose_w_kernel<<<dim3(8, 16), tb, 0, stream>>>(Wkv, 1024, 0, 1024, Wqkv_t + 512 * 1024);
  transpose_w_kernel<<<dim3(8, 16), tb, 0, stream>>>(Wkv, 1024, 512, 1024, Wqkv_t + 1024 * 1024);
  transpose_w_kernel<<<dim3(16, 8), tb, 0, stream>>>(Wo, 1024, 0, 512, Wo_t);

  // fused QKV projection + l2norm: [8192 x 1536 x 1024]
  gemm_kernel<1><<<dim3(64, 12), 256, 0, stream>>>(xh, Wqkv_t, nullptr, Qb, Kb, Vb,
                                                   8192, 1536, 1024);
  // V -> V^T (xh space is dead now)
  transpose_v_kernel<<<dim3(64, 16), 256, 0, stream>>>(Vb, Vt, 4096);
  // attention
  attn_kernel<<<dim3(32, 16), 256, 0, stream>>>(Qb, Kb, Vt, At, 4096);
  // output projection: [8192 x 1024 x 512]
  gemm_kernel<0><<<dim3(64, 8), 256, 0, stream>>>(At, Wo_t, out, nullptr, nullptr, nullptr,
                                                  8192, 1024, 512);
}

// Round 3
// 173.774 us; speedup vs baseline: 1.1036x; 1.0005x over previous
//
#include <hip/hip_runtime.h>

// ---------------------------------------------------------------------------
// FlashAttention_45844480917693 — cosine-sim attention, MI355X (gfx950)
// R3: attn goes 8 waves x 16 q-rows (512 threads) — halves per-wave serial
// chain, doubles waves/SIMD (2->4) for latency hiding. Swapped QK^T, packed
// P writes, pre-transposed V, double-buffered K/V with prefetch-before-
// compute, one barrier/tile. fp16 MFMA, fp32 accum.
// ---------------------------------------------------------------------------

typedef _Float16 f16;
typedef _Float16 f16x4 __attribute__((ext_vector_type(4)));
typedef _Float16 f16x8 __attribute__((ext_vector_type(8)));
typedef float f32x4 __attribute__((ext_vector_type(4)));

#define MFMA_F16(a, b, c) __builtin_amdgcn_mfma_f32_16x16x32_f16((a), (b), (c), 0, 0, 0)

__device__ __forceinline__ void gl_lds16(const void* g, void* l) {
  // async global->LDS, 16B per lane; LDS dest = wave-uniform base + lane*16
  __builtin_amdgcn_global_load_lds(
      (const __attribute__((address_space(1))) void*)g,
      (__attribute__((address_space(3))) void*)l, 16, 0, 0);
}

// ---------------------------------------------------------------------------
// x (fp32) -> fp16, 8 elements/thread
__global__ void convert_x_kernel(const float* __restrict__ x, f16* __restrict__ xh, int n8) {
  int i = blockIdx.x * 256 + threadIdx.x;
  if (i >= n8) return;
  const float4* xv = (const float4*)x;
  float4 a = xv[2 * i], b = xv[2 * i + 1];
  f16x8 o;
  o[0] = (f16)a.x; o[1] = (f16)a.y; o[2] = (f16)a.z; o[3] = (f16)a.w;
  o[4] = (f16)b.x; o[5] = (f16)b.y; o[6] = (f16)b.z; o[7] = (f16)b.w;
  ((f16x8*)xh)[i] = o;
}

// W [K][ldw] fp32, take cols [col0, col0+gridDim.x*64) -> out[c][k] fp16 ([out][in])
__global__ void transpose_w_kernel(const float* __restrict__ W, int ldw, int col0,
                                   int K, f16* __restrict__ out) {
  __shared__ float t[64][65];
  int tx = threadIdx.x, ty = threadIdx.y;
  int c0 = blockIdx.x * 64, k0 = blockIdx.y * 64;
#pragma unroll
  for (int i = 0; i < 8; i++)
    t[ty + i * 8][tx] = W[(long)(k0 + ty + i * 8) * ldw + col0 + c0 + tx];
  __syncthreads();
#pragma unroll
  for (int i = 0; i < 8; i++)
    out[(long)(c0 + ty + i * 8) * K + k0 + tx] = (f16)t[tx][ty + i * 8];
}

// Vb [bh][n][64] -> Vt [bh][64][n], 64x64 f16 tiles, swizzled LDS
__global__ void transpose_v_kernel(const f16* __restrict__ Vb, f16* __restrict__ Vt, int n) {
  __shared__ f16 t[64 * 64];
  const int tid = threadIdx.x;
  const int bh = blockIdx.y;
  const int n0 = blockIdx.x * 64;
  const f16* src = Vb + ((long)bh * n + n0) * 64;
  const int j = tid >> 3, c = tid & 7;
  f16x8 v0 = *(const f16x8*)(src + j * 64 + c * 8);
  f16x8 v1 = *(const f16x8*)(src + (j + 32) * 64 + c * 8);
  *(f16x8*)(&t[j * 64 + ((c ^ (j & 7)) << 3)]) = v0;
  *(f16x8*)(&t[(j + 32) * 64 + ((c ^ (j & 7)) << 3)]) = v1;  // (j+32)&7 == j&7
  __syncthreads();
  const int d = tid >> 3, cj = tid & 7;
  f16x8 o0, o1;
#pragma unroll
  for (int e = 0; e < 8; e++) {
    int jj = cj * 8 + e;
    o0[e] = t[jj * 64 + (((d >> 3) ^ (jj & 7)) << 3) + (d & 7)];
    o1[e] = t[jj * 64 + ((((d + 32) >> 3) ^ (jj & 7)) << 3) + ((d + 32) & 7)];
  }
  *(f16x8*)(Vt + ((long)bh * 64 + d) * n + n0 + cj * 8) = o0;
  *(f16x8*)(Vt + ((long)bh * 64 + d + 32) * n + n0 + cj * 8) = o1;
}

// ---------------------------------------------------------------------------
// GEMM: C[M][N] = A[M][K] * Bt[N][K]^T, 128x128 tile, BK=32, 4 waves (2x2),
// MODE 0: fp32 C out. MODE 1: fused QKV epilogue (l2norm for Q/K).
template <int MODE>
__global__ __launch_bounds__(256, 2)
void gemm_kernel(const f16* __restrict__ A, const f16* __restrict__ Bt,
                 float* __restrict__ C,
                 f16* __restrict__ Qb, f16* __restrict__ Kb, f16* __restrict__ Vb,
                 int M, int N, int K) {
  __shared__ f16 As[128 * 32];
  __shared__ f16 Bs[128 * 32];
  const int tid = threadIdx.x;
  const int lane = tid & 63;
  const int wid = tid >> 6;
  const int wr = wid >> 1, wc = wid & 1;
  const int lr = lane & 15, lk = lane >> 4;
  const long m0 = (long)blockIdx.x * 128;
  const int n0 = blockIdx.y * 128;

  f32x4 acc[4][4] = {};

  const int c0 = tid, c1 = tid + 256;
  const int ar0 = c0 >> 2, ah0 = (c0 & 3) ^ ((ar0 >> 1) & 3);
  const int ar1 = c1 >> 2, ah1 = (c1 & 3) ^ ((ar1 >> 1) & 3);
  const f16* pa0 = A + (m0 + ar0) * K + ah0 * 8;
  const f16* pa1 = A + (m0 + ar1) * K + ah1 * 8;
  const f16* pb0 = Bt + (long)(n0 + ar0) * K + ah0 * 8;
  const f16* pb1 = Bt + (long)(n0 + ar1) * K + ah1 * 8;

  for (int k0 = 0; k0 < K; k0 += 32) {
    __syncthreads();
    gl_lds16(pa0 + k0, As + c0 * 8);
    gl_lds16(pa1 + k0, As + c1 * 8);
    gl_lds16(pb0 + k0, Bs + c0 * 8);
    gl_lds16(pb1 + k0, Bs + c1 * 8);
    __syncthreads();

    f16x8 af[4], bf[4];
#pragma unroll
    for (int mi = 0; mi < 4; mi++) {
      int row = wr * 64 + mi * 16 + lr;
      int ch = lk ^ ((row >> 1) & 3);
      af[mi] = *(const f16x8*)(As + row * 32 + ch * 8);
    }
#pragma unroll
    for (int ni = 0; ni < 4; ni++) {
      int row = wc * 64 + ni * 16 + lr;
      int ch = lk ^ ((row >> 1) & 3);
      bf[ni] = *(const f16x8*)(Bs + row * 32 + ch * 8);
    }
#pragma unroll
    for (int mi = 0; mi < 4; mi++)
#pragma unroll
      for (int ni = 0; ni < 4; ni++)
        acc[mi][ni] = MFMA_F16(af[mi], bf[ni], acc[mi][ni]);
  }

  if (MODE == 0) {
#pragma unroll
    for (int mi = 0; mi < 4; mi++) {
      long mrow = m0 + wr * 64 + mi * 16 + lk * 4;
#pragma unroll
      for (int r = 0; r < 4; r++)
#pragma unroll
        for (int ni = 0; ni < 4; ni++)
          C[(mrow + r) * N + n0 + wc * 64 + ni * 16 + lr] = acc[mi][ni][r];
    }
  } else {
    const int region = blockIdx.y >> 2;              // 0=Q, 1=K, 2=V
    const int head = (blockIdx.y & 3) * 2 + wc;
    f16* buf = (region == 0) ? Qb : ((region == 1) ? Kb : Vb);
#pragma unroll
    for (int mi = 0; mi < 4; mi++) {
      float scl[4];
      if (region < 2) {
#pragma unroll
        for (int r = 0; r < 4; r++) {
          float s2 = 0.f;
#pragma unroll
          for (int ni = 0; ni < 4; ni++) s2 += acc[mi][ni][r] * acc[mi][ni][r];
          s2 += __shfl_xor(s2, 1);
          s2 += __shfl_xor(s2, 2);
          s2 += __shfl_xor(s2, 4);
          s2 += __shfl_xor(s2, 8);
          scl[r] = 1.f / fmaxf(sqrtf(s2), 1e-12f);
        }
      } else {
#pragma unroll
        for (int r = 0; r < 4; r++) scl[r] = 1.f;
      }
#pragma unroll
      for (int r = 0; r < 4; r++) {
        int m = (int)m0 + wr * 64 + mi * 16 + lk * 4 + r;
        int bb = m >> 12, nn = m & 4095;
        f16* dst = buf + (((long)(bb * 8 + head) * 4096 + nn) << 6);
#pragma unroll
        for (int ni = 0; ni < 4; ni++)
          dst[ni * 16 + lr] = (f16)(acc[mi][ni][r] * scl[r]);
      }
    }
  }
}

// ---------------------------------------------------------------------------
// Attention v3. grid (n/128, b*h), 8 waves x 16 q-rows (512 threads).
// Double-buffered K/V (prefetch before compute, one barrier/tile). Swapped
// QK^T (rows=j, cols=q) -> packed P (cvt_pkrtz + b64 writes). V comes
// pre-transposed (Vt [bh][64][n]). P scaled by 2^14 (cancels in rowsum div).
__global__ __launch_bounds__(512, 2)
void attn_kernel(const f16* __restrict__ Qb, const f16* __restrict__ Kb,
                 const f16* __restrict__ Vt, f16* __restrict__ Ob, int n) {
  __shared__ f16 Ks[2][64 * 64];     // [j][d], chunk ^= (j&7)
  __shared__ f16 Vs[2][64 * 64];     // [d][j], chunk ^= (d&7)
  __shared__ f16 Ps[8][16 * 64];     // per-wave [q][j], 16B-chunk ^= (q&7)
  const int tid = threadIdx.x, lane = tid & 63, wid = tid >> 6;
  const int lr = lane & 15, lk = lane >> 4;
  const int bh = blockIdx.y;
  const long nl = n;
  const f16* Qg = Qb + (long)bh * nl * 64;
  const f16* Kg = Kb + (long)bh * nl * 64;
  const f16* Vg = Vt + (long)bh * 64 * nl;
  const int q0 = blockIdx.x * 128 + wid * 16;

  // Q fragments (B-operand of swapped QK^T): col q = lr, k d = kc*32+lk*8+e
  f16x8 qf[2];
#pragma unroll
  for (int kc = 0; kc < 2; kc++)
    qf[kc] = *(const f16x8*)(Qg + (long)(q0 + lr) * 64 + kc * 32 + lk * 8);

  const int sr = tid >> 3;              // staging row 0..63
  const int sc = (tid & 7) ^ (sr & 7);  // pre-swizzled source chunk

  f32x4 oacc[4] = {};
  float rsum = 0.f;

  // prologue: stage tile 0 into buf 0 (one K + one V gl_lds per thread)
  gl_lds16(Kg + (long)sr * 64 + sc * 8, &Ks[0][tid * 8]);
  gl_lds16(Vg + (long)sr * nl + sc * 8, &Vs[0][tid * 8]);
  __syncthreads();

  const int nt = n >> 6;
  for (int t = 0; t < nt; t++) {
    const int cur = t & 1;
    // prefetch tile t+1 into the other buffer — overlaps ALL of compute(t)
    if (t + 1 < nt) {
      const long j0 = (long)(t + 1) << 6;
      gl_lds16(Kg + (j0 + sr) * 64 + sc * 8, &Ks[cur ^ 1][tid * 8]);
      gl_lds16(Vg + (long)sr * nl + j0 + sc * 8, &Vs[cur ^ 1][tid * 8]);
    }

    // S^T = K * Q^T : rows j (regs), cols q (lanes)
    f32x4 s[4] = {};
#pragma unroll
    for (int kc = 0; kc < 2; kc++)
#pragma unroll
      for (int jt = 0; jt < 4; jt++) {
        const int j = jt * 16 + lr;
        const f16x8 kf =
            *(const f16x8*)(&Ks[cur][j * 64 + (((kc * 4 + lk) ^ (j & 7)) << 3)]);
        s[jt] = MFMA_F16(kf, qf[kc], s[jt]);
      }

    // p' = 2^(16*log2e*(s-1) + 14); rowsum; pack 4 f16 -> one b64 LDS write
#pragma unroll
    for (int jt = 0; jt < 4; jt++) {
      const f32x4 sv = s[jt];
      const float p0 = __builtin_amdgcn_exp2f(fmaf(sv[0], 23.083120654223414f, -9.083120654223414f));
      const float p1 = __builtin_amdgcn_exp2f(fmaf(sv[1], 23.083120654223414f, -9.083120654223414f));
      const float p2 = __builtin_amdgcn_exp2f(fmaf(sv[2], 23.083120654223414f, -9.083120654223414f));
      const float p3 = __builtin_amdgcn_exp2f(fmaf(sv[3], 23.083120654223414f, -9.083120654223414f));
      rsum += (p0 + p1) + (p2 + p3);
      const auto h01 = __builtin_amdgcn_cvt_pkrtz(p0, p1);
      const auto h23 = __builtin_amdgcn_cvt_pkrtz(p2, p3);
      f16x4 pk;
      pk[0] = h01[0]; pk[1] = h01[1]; pk[2] = h23[0]; pk[3] = h23[1];
      const int c16 = jt * 2 + (lk >> 1);
      *(f16x4*)(&Ps[wid][lr * 64 + ((c16 ^ (lr & 7)) << 3) + ((lk & 1) << 2)]) = pk;
    }

    // O += P * V : A = P (row q, k j), B = V^T rows (col d, k j)
#pragma unroll
    for (int kc = 0; kc < 2; kc++) {
      const int c16 = kc * 4 + lk;
      const f16x8 pa = *(const f16x8*)(&Ps[wid][lr * 64 + ((c16 ^ (lr & 7)) << 3)]);
      f16x8 vf[4];
#pragma unroll
      for (int dt = 0; dt < 4; dt++) {
        const int d = dt * 16 + lr;
        vf[dt] = *(const f16x8*)(&Vs[cur][d * 64 + ((c16 ^ (d & 7)) << 3)]);
      }
#pragma unroll
      for (int dt = 0; dt < 4; dt++)
        oacc[dt] = MFMA_F16(pa, vf[dt], oacc[dt]);
    }

    __syncthreads();  // drains prefetch vmcnt + all waves done with buf[cur]
  }

  // rowsum reduce over the 4 lk groups, redistribute to output layout, store
  rsum += __shfl_xor(rsum, 16);
  rsum += __shfl_xor(rsum, 32);
  const int bb = bh >> 3, hh = bh & 7;
#pragma unroll
  for (int r = 0; r < 4; r++) {
    const float sm = __shfl(rsum, lk * 4 + r);           // sum for q-row lk*4+r
    const float inv = 1.f / fmaxf(sm, 0.016384f);        // 1e-6 * 2^14
    const int qq = q0 + lk * 4 + r;
    f16* dst = Ob + (((long)(bb * 4096 + qq)) << 9) + hh * 64;
#pragma unroll
    for (int dt = 0; dt < 4; dt++)
      dst[dt * 16 + lr] = (f16)(oacc[dt][r] * inv);
  }
}

// ---------------------------------------------------------------------------
extern "C" void kernel_launch(void* const* d_in, const int* in_sizes, int n_in,
                              void* d_out, int out_size, void* d_ws, size_t ws_size,
                              hipStream_t stream) {
  const float* x   = (const float*)d_in[0];   // [2,4096,1024]
  const float* Wq  = (const float*)d_in[1];   // [1024,512]
  const float* Wkv = (const float*)d_in[2];   // [1024,1024]
  const float* Wo  = (const float*)d_in[3];   // [512,1024]
  float* out = (float*)d_out;                 // [2,4096,1024] fp32

  char* ws = (char*)d_ws;
  f16* xh     = (f16*)(ws);                   // 16.78 MB  [8192][1024]; reused as Vt after QKV GEMM
  f16* Wqkv_t = (f16*)(ws + 16777216);        //  3.15 MB  [1536][1024]
  f16* Wo_t   = (f16*)(ws + 19922944);        //  1.05 MB  [1024][512]
  f16* Qb     = (f16*)(ws + 20971520);        //  8.39 MB  [16][4096][64]
  f16* Kb     = (f16*)(ws + 29360128);        //  8.39 MB
  f16* Vb     = (f16*)(ws + 37748736);        //  8.39 MB
  f16* At     = (f16*)(ws + 46137344);        //  8.39 MB  [8192][512]
  f16* Vt     = xh;                           //  8.39 MB  [16][64][4096] (xh dead after QKV GEMM)

  convert_x_kernel<<<4096, 256, 0, stream>>>(x, xh, 1048576);

  dim3 tb(64, 8);
  transpose_w_kernel<<<dim3(8, 16), tb, 0, stream>>>(Wq, 512, 0, 1024, Wqkv_t);
  transpose_w_kernel<<<dim3(8, 16), tb, 0, stream>>>(Wkv, 1024, 0, 1024, Wqkv_t + 512 * 1024);
  transpose_w_kernel<<<dim3(8, 16), tb, 0, stream>>>(Wkv, 1024, 512, 1024, Wqkv_t + 1024 * 1024);
  transpose_w_kernel<<<dim3(16, 8), tb, 0, stream>>>(Wo, 1024, 0, 512, Wo_t);

  // fused QKV projection + l2norm: [8192 x 1536 x 1024]
  gemm_kernel<1><<<dim3(64, 12), 256, 0, stream>>>(xh, Wqkv_t, nullptr, Qb, Kb, Vb,
                                                   8192, 1536, 1024);
  // V -> V^T (xh space is dead now)
  transpose_v_kernel<<<dim3(64, 16), 256, 0, stream>>>(Vb, Vt, 4096);
  // attention
  attn_kernel<<<dim3(32, 16), 512, 0, stream>>>(Qb, Kb, Vt, At, 4096);
  // output projection: [8192 x 1024 x 512]
  gemm_kernel<0><<<dim3(64, 8), 256, 0, stream>>>(At, Wo_t, out, nullptr, nullptr, nullptr,
                                                  8192, 1024, 512);
}

// Round 5
// 170.188 us; speedup vs baseline: 1.1269x; 1.0211x over previous
//
#include <hip/hip_runtime.h>

// ---------------------------------------------------------------------------
// FlashAttention_45844480917693 — cosine-sim attention, MI355X (gfx950)
// R4b: (compile fix of R4) attn KVBLK=128 (one barrier per 128 keys, 2x
// prefetch window), XCD-aware block remap (all q-blocks of a head on one XCD
// -> K/V L2-resident), setprio around MFMA clusters. 8 waves x 16 q-rows,
// swapped QK^T, packed P, pre-transposed V, double-buffered K/V.
// ---------------------------------------------------------------------------

typedef _Float16 f16;
typedef _Float16 f16x4 __attribute__((ext_vector_type(4)));
typedef _Float16 f16x8 __attribute__((ext_vector_type(8)));
typedef float f32x4 __attribute__((ext_vector_type(4)));

#define MFMA_F16(a, b, c) __builtin_amdgcn_mfma_f32_16x16x32_f16((a), (b), (c), 0, 0, 0)

__device__ __forceinline__ void gl_lds16(const void* g, void* l) {
  // async global->LDS, 16B per lane; LDS dest = wave-uniform base + lane*16
  __builtin_amdgcn_global_load_lds(
      (const __attribute__((address_space(1))) void*)g,
      (__attribute__((address_space(3))) void*)l, 16, 0, 0);
}

// ---------------------------------------------------------------------------
// x (fp32) -> fp16, 8 elements/thread
__global__ void convert_x_kernel(const float* __restrict__ x, f16* __restrict__ xh, int n8) {
  int i = blockIdx.x * 256 + threadIdx.x;
  if (i >= n8) return;
  const float4* xv = (const float4*)x;
  float4 a = xv[2 * i], b = xv[2 * i + 1];
  f16x8 o;
  o[0] = (f16)a.x; o[1] = (f16)a.y; o[2] = (f16)a.z; o[3] = (f16)a.w;
  o[4] = (f16)b.x; o[5] = (f16)b.y; o[6] = (f16)b.z; o[7] = (f16)b.w;
  ((f16x8*)xh)[i] = o;
}

// W [K][ldw] fp32, take cols [col0, col0+gridDim.x*64) -> out[c][k] fp16 ([out][in])
__global__ void transpose_w_kernel(const float* __restrict__ W, int ldw, int col0,
                                   int K, f16* __restrict__ out) {
  __shared__ float t[64][65];
  int tx = threadIdx.x, ty = threadIdx.y;
  int c0 = blockIdx.x * 64, k0 = blockIdx.y * 64;
#pragma unroll
  for (int i = 0; i < 8; i++)
    t[ty + i * 8][tx] = W[(long)(k0 + ty + i * 8) * ldw + col0 + c0 + tx];
  __syncthreads();
#pragma unroll
  for (int i = 0; i < 8; i++)
    out[(long)(c0 + ty + i * 8) * K + k0 + tx] = (f16)t[tx][ty + i * 8];
}

// Vb [bh][n][64] -> Vt [bh][64][n], 64x64 f16 tiles, swizzled LDS
__global__ void transpose_v_kernel(const f16* __restrict__ Vb, f16* __restrict__ Vt, int n) {
  __shared__ f16 t[64 * 64];
  const int tid = threadIdx.x;
  const int bh = blockIdx.y;
  const int n0 = blockIdx.x * 64;
  const f16* src = Vb + ((long)bh * n + n0) * 64;
  const int j = tid >> 3, c = tid & 7;
  f16x8 v0 = *(const f16x8*)(src + j * 64 + c * 8);
  f16x8 v1 = *(const f16x8*)(src + (j + 32) * 64 + c * 8);
  *(f16x8*)(&t[j * 64 + ((c ^ (j & 7)) << 3)]) = v0;
  *(f16x8*)(&t[(j + 32) * 64 + ((c ^ (j & 7)) << 3)]) = v1;  // (j+32)&7 == j&7
  __syncthreads();
  const int d = tid >> 3, cj = tid & 7;
  f16x8 o0, o1;
#pragma unroll
  for (int e = 0; e < 8; e++) {
    int jj = cj * 8 + e;
    o0[e] = t[jj * 64 + (((d >> 3) ^ (jj & 7)) << 3) + (d & 7)];
    o1[e] = t[jj * 64 + ((((d + 32) >> 3) ^ (jj & 7)) << 3) + ((d + 32) & 7)];
  }
  *(f16x8*)(Vt + ((long)bh * 64 + d) * n + n0 + cj * 8) = o0;
  *(f16x8*)(Vt + ((long)bh * 64 + d + 32) * n + n0 + cj * 8) = o1;
}

// ---------------------------------------------------------------------------
// GEMM: C[M][N] = A[M][K] * Bt[N][K]^T, 128x128 tile, BK=32, 4 waves (2x2),
// MODE 0: fp32 C out. MODE 1: fused QKV epilogue (l2norm for Q/K).
// 1-D grid, XCD-aware decode: x-panels grouped per XCD (A chunk L2-resident).
template <int MODE>
__global__ __launch_bounds__(256, 2)
void gemm_kernel(const f16* __restrict__ A, const f16* __restrict__ Bt,
                 float* __restrict__ C,
                 f16* __restrict__ Qb, f16* __restrict__ Kb, f16* __restrict__ Vb,
                 int M, int N, int K) {
  __shared__ f16 As[128 * 32];
  __shared__ f16 Bs[128 * 32];
  const int tid = threadIdx.x;
  const int lane = tid & 63;
  const int wid = tid >> 6;
  const int wr = wid >> 1, wc = wid & 1;
  const int lr = lane & 15, lk = lane >> 4;
  const int lin = blockIdx.x;
  const int bx = ((lin & 7) << 3) | ((lin >> 3) & 7);  // XCD (lin%8) owns 8 x-panels
  const int by = lin >> 6;
  const long m0 = (long)bx * 128;
  const int n0 = by * 128;

  f32x4 acc[4][4] = {};

  const int c0 = tid, c1 = tid + 256;
  const int ar0 = c0 >> 2, ah0 = (c0 & 3) ^ ((ar0 >> 1) & 3);
  const int ar1 = c1 >> 2, ah1 = (c1 & 3) ^ ((ar1 >> 1) & 3);
  const f16* pa0 = A + (m0 + ar0) * K + ah0 * 8;
  const f16* pa1 = A + (m0 + ar1) * K + ah1 * 8;
  const f16* pb0 = Bt + (long)(n0 + ar0) * K + ah0 * 8;
  const f16* pb1 = Bt + (long)(n0 + ar1) * K + ah1 * 8;

  for (int k0 = 0; k0 < K; k0 += 32) {
    __syncthreads();
    gl_lds16(pa0 + k0, As + c0 * 8);
    gl_lds16(pa1 + k0, As + c1 * 8);
    gl_lds16(pb0 + k0, Bs + c0 * 8);
    gl_lds16(pb1 + k0, Bs + c1 * 8);
    __syncthreads();

    f16x8 af[4], bf[4];
#pragma unroll
    for (int mi = 0; mi < 4; mi++) {
      int row = wr * 64 + mi * 16 + lr;
      int ch = lk ^ ((row >> 1) & 3);
      af[mi] = *(const f16x8*)(As + row * 32 + ch * 8);
    }
#pragma unroll
    for (int ni = 0; ni < 4; ni++) {
      int row = wc * 64 + ni * 16 + lr;
      int ch = lk ^ ((row >> 1) & 3);
      bf[ni] = *(const f16x8*)(Bs + row * 32 + ch * 8);
    }
    __builtin_amdgcn_s_setprio(1);
#pragma unroll
    for (int mi = 0; mi < 4; mi++)
#pragma unroll
      for (int ni = 0; ni < 4; ni++)
        acc[mi][ni] = MFMA_F16(af[mi], bf[ni], acc[mi][ni]);
    __builtin_amdgcn_s_setprio(0);
  }

  if (MODE == 0) {
#pragma unroll
    for (int mi = 0; mi < 4; mi++) {
      long mrow = m0 + wr * 64 + mi * 16 + lk * 4;
#pragma unroll
      for (int r = 0; r < 4; r++)
#pragma unroll
        for (int ni = 0; ni < 4; ni++)
          C[(mrow + r) * N + n0 + wc * 64 + ni * 16 + lr] = acc[mi][ni][r];
    }
  } else {
    const int region = by >> 2;                      // 0=Q, 1=K, 2=V
    const int head = (by & 3) * 2 + wc;
    f16* buf = (region == 0) ? Qb : ((region == 1) ? Kb : Vb);
#pragma unroll
    for (int mi = 0; mi < 4; mi++) {
      float scl[4];
      if (region < 2) {
#pragma unroll
        for (int r = 0; r < 4; r++) {
          float s2 = 0.f;
#pragma unroll
          for (int ni = 0; ni < 4; ni++) s2 += acc[mi][ni][r] * acc[mi][ni][r];
          s2 += __shfl_xor(s2, 1);
          s2 += __shfl_xor(s2, 2);
          s2 += __shfl_xor(s2, 4);
          s2 += __shfl_xor(s2, 8);
          scl[r] = 1.f / fmaxf(sqrtf(s2), 1e-12f);
        }
      } else {
#pragma unroll
        for (int r = 0; r < 4; r++) scl[r] = 1.f;
      }
#pragma unroll
      for (int r = 0; r < 4; r++) {
        int m = (int)m0 + wr * 64 + mi * 16 + lk * 4 + r;
        int bb = m >> 12, nn = m & 4095;
        f16* dst = buf + (((long)(bb * 8 + head) * 4096 + nn) << 6);
#pragma unroll
        for (int ni = 0; ni < 4; ni++)
          dst[ni * 16 + lr] = (f16)(acc[mi][ni][r] * scl[r]);
      }
    }
  }
}

// ---------------------------------------------------------------------------
// Attention v4. 1-D grid of 512; decode bh = (lin&7)|((lin>>8)<<3) so each
// XCD owns 2 heads (K+V = 2MB -> L2-resident). 8 waves x 16 q-rows.
// KVBLK=128: one barrier per 128 keys; softmax+PV in two 64-j sub-tiles
// (Ps reused per sub-tile; per-wave DS FIFO ordering). Double-buffered K/V,
// prefetch before compute. Swapped QK^T, packed P (cvt_pkrtz + b64), V
// pre-transposed. P scaled by 2^14 (cancels in rowsum division).
__global__ __launch_bounds__(512, 4)
void attn_kernel(const f16* __restrict__ Qb, const f16* __restrict__ Kb,
                 const f16* __restrict__ Vt, f16* __restrict__ Ob, int n) {
  __shared__ f16 Ks[2][128 * 64];    // [j][d], 16B-chunk ^= (j&7)       16KB x2
  __shared__ f16 Vs[2][64 * 128];    // [d][j], 16B-chunk ^= (d&15)      16KB x2
  __shared__ f16 Ps[8][16 * 64];     // per-wave [q][j], chunk ^= (q&7)  16KB
  const int tid = threadIdx.x, lane = tid & 63, wid = tid >> 6;
  const int lr = lane & 15, lk = lane >> 4;
  const int lin = blockIdx.x;
  const int bh = (lin & 7) | ((lin >> 8) << 3);
  const int qx = (lin >> 3) & 31;
  const long nl = n;
  const f16* Qg = Qb + (long)bh * nl * 64;
  const f16* Kg = Kb + (long)bh * nl * 64;
  const f16* Vg = Vt + (long)bh * 64 * nl;
  const int q0 = qx * 128 + wid * 16;

  // Q fragments (B-operand of swapped QK^T): col q = lr, k d = kc*32+lk*8+e
  f16x8 qf[2];
#pragma unroll
  for (int kc = 0; kc < 2; kc++)
    qf[kc] = *(const f16x8*)(Qg + (long)(q0 + lr) * 64 + kc * 32 + lk * 8);

  // staging: dst is always lds_base + tid*8 (+4096 for 2nd pass); source
  // pre-swizzled so LDS stays lane-linear.
  const int krow = tid >> 3;                          // 0..63 (+64 2nd pass)
  const int kcol = ((tid & 7) ^ (krow & 7)) * 8;
  const int vrow = tid >> 4;                          // 0..31 (+32 2nd pass)
  const int vcol = ((tid & 15) ^ (vrow & 15)) * 8;

  f32x4 oacc[4] = {};
  float rsum = 0.f;
  const f32x4 zero4 = {0.f, 0.f, 0.f, 0.f};

  // prologue: stage tile 0 into buf 0
  gl_lds16(Kg + (long)krow * 64 + kcol, &Ks[0][tid * 8]);
  gl_lds16(Kg + (long)(krow + 64) * 64 + kcol, &Ks[0][tid * 8 + 4096]);
  gl_lds16(Vg + (long)vrow * nl + vcol, &Vs[0][tid * 8]);
  gl_lds16(Vg + (long)(vrow + 32) * nl + vcol, &Vs[0][tid * 8 + 4096]);
  __syncthreads();

  const int nt = n >> 7;
  for (int t = 0; t < nt; t++) {
    const int cur = t & 1;
    // prefetch tile t+1 — overlaps ALL of compute(t)
    if (t + 1 < nt) {
      const long j0 = (long)(t + 1) << 7;
      gl_lds16(Kg + (j0 + krow) * 64 + kcol, &Ks[cur ^ 1][tid * 8]);
      gl_lds16(Kg + (j0 + krow + 64) * 64 + kcol, &Ks[cur ^ 1][tid * 8 + 4096]);
      gl_lds16(Vg + (long)vrow * nl + j0 + vcol, &Vs[cur ^ 1][tid * 8]);
      gl_lds16(Vg + (long)(vrow + 32) * nl + j0 + vcol, &Vs[cur ^ 1][tid * 8 + 4096]);
    }

    // S^T = K * Q^T over all 128 j: rows j (regs), cols q (lanes)
    f32x4 s[8];
    __builtin_amdgcn_s_setprio(1);
#pragma unroll
    for (int jt = 0; jt < 8; jt++) {
      const int j = jt * 16 + lr;
      const f16x8 kf0 = *(const f16x8*)(&Ks[cur][j * 64 + ((lk ^ (j & 7)) << 3)]);
      const f16x8 kf1 = *(const f16x8*)(&Ks[cur][j * 64 + (((4 + lk) ^ (j & 7)) << 3)]);
      f32x4 acc0 = MFMA_F16(kf0, qf[0], zero4);
      s[jt] = MFMA_F16(kf1, qf[1], acc0);
    }
    __builtin_amdgcn_s_setprio(0);

    // two 64-j sub-tiles: softmax -> Ps -> PV (Ps reused; per-wave DS FIFO)
#pragma unroll
    for (int sub = 0; sub < 2; sub++) {
#pragma unroll
      for (int jt2 = 0; jt2 < 4; jt2++) {
        const f32x4 sv = s[sub * 4 + jt2];
        const float p0 = __builtin_amdgcn_exp2f(fmaf(sv[0], 23.083120654223414f, -9.083120654223414f));
        const float p1 = __builtin_amdgcn_exp2f(fmaf(sv[1], 23.083120654223414f, -9.083120654223414f));
        const float p2 = __builtin_amdgcn_exp2f(fmaf(sv[2], 23.083120654223414f, -9.083120654223414f));
        const float p3 = __builtin_amdgcn_exp2f(fmaf(sv[3], 23.083120654223414f, -9.083120654223414f));
        rsum += (p0 + p1) + (p2 + p3);
        const auto h01 = __builtin_amdgcn_cvt_pkrtz(p0, p1);
        const auto h23 = __builtin_amdgcn_cvt_pkrtz(p2, p3);
        f16x4 pk;
        pk[0] = h01[0]; pk[1] = h01[1]; pk[2] = h23[0]; pk[3] = h23[1];
        const int c16 = jt2 * 2 + (lk >> 1);
        *(f16x4*)(&Ps[wid][lr * 64 + ((c16 ^ (lr & 7)) << 3) + ((lk & 1) << 2)]) = pk;
      }

      __builtin_amdgcn_s_setprio(1);
#pragma unroll
      for (int kc2 = 0; kc2 < 2; kc2++) {
        const int c16 = kc2 * 4 + lk;
        const f16x8 pa = *(const f16x8*)(&Ps[wid][lr * 64 + ((c16 ^ (lr & 7)) << 3)]);
        f16x8 vf[4];
#pragma unroll
        for (int dt = 0; dt < 4; dt++) {
          const int d = dt * 16 + lr;
          vf[dt] = *(const f16x8*)(&Vs[cur][d * 128 + (((sub * 8 + kc2 * 4 + lk) ^ (d & 15)) << 3)]);
        }
#pragma unroll
        for (int dt = 0; dt < 4; dt++)
          oacc[dt] = MFMA_F16(pa, vf[dt], oacc[dt]);
      }
      __builtin_amdgcn_s_setprio(0);
    }

    __syncthreads();  // drains prefetch vmcnt + all waves done with buf[cur]
  }

  // rowsum reduce over the 4 lk groups, redistribute to output layout, store
  rsum += __shfl_xor(rsum, 16);
  rsum += __shfl_xor(rsum, 32);
  const int bb = bh >> 3, hh = bh & 7;
#pragma unroll
  for (int r = 0; r < 4; r++) {
    const float sm = __shfl(rsum, lk * 4 + r);           // sum for q-row lk*4+r
    const float inv = 1.f / fmaxf(sm, 0.016384f);        // 1e-6 * 2^14
    const int qq = q0 + lk * 4 + r;
    f16* dst = Ob + (((long)(bb * 4096 + qq)) << 9) + hh * 64;
#pragma unroll
    for (int dt = 0; dt < 4; dt++)
      dst[dt * 16 + lr] = (f16)(oacc[dt][r] * inv);
  }
}

// ---------------------------------------------------------------------------
extern "C" void kernel_launch(void* const* d_in, const int* in_sizes, int n_in,
                              void* d_out, int out_size, void* d_ws, size_t ws_size,
                              hipStream_t stream) {
  const float* x   = (const float*)d_in[0];   // [2,4096,1024]
  const float* Wq  = (const float*)d_in[1];   // [1024,512]
  const float* Wkv = (const float*)d_in[2];   // [1024,1024]
  const float* Wo  = (const float*)d_in[3];   // [512,1024]
  float* out = (float*)d_out;                 // [2,4096,1024] fp32

  char* ws = (char*)d_ws;
  f16* xh     = (f16*)(ws);                   // 16.78 MB  [8192][1024]; reused as Vt after QKV GEMM
  f16* Wqkv_t = (f16*)(ws + 16777216);        //  3.15 MB  [1536][1024]
  f16* Wo_t   = (f16*)(ws + 19922944);        //  1.05 MB  [1024][512]
  f16* Qb     = (f16*)(ws + 20971520);        //  8.39 MB  [16][4096][64]
  f16* Kb     = (f16*)(ws + 29360128);        //  8.39 MB
  f16* Vb     = (f16*)(ws + 37748736);        //  8.39 MB
  f16* At     = (f16*)(ws + 46137344);        //  8.39 MB  [8192][512]
  f16* Vt     = xh;                           //  8.39 MB  [16][64][4096] (xh dead after QKV GEMM)

  convert_x_kernel<<<4096, 256, 0, stream>>>(x, xh, 1048576);

  dim3 tb(64, 8);
  transpose_w_kernel<<<dim3(8, 16), tb, 0, stream>>>(Wq, 512, 0, 1024, Wqkv_t);
  transpose_w_kernel<<<dim3(8, 16), tb, 0, stream>>>(Wkv, 1024, 0, 1024, Wqkv_t + 512 * 1024);
  transpose_w_kernel<<<dim3(8, 16), tb, 0, stream>>>(Wkv, 1024, 512, 1024, Wqkv_t + 1024 * 1024);
  transpose_w_kernel<<<dim3(16, 8), tb, 0, stream>>>(Wo, 1024, 0, 512, Wo_t);

  // fused QKV projection + l2norm: [8192 x 1536 x 1024]  (768 = 64x * 12y)
  gemm_kernel<1><<<768, 256, 0, stream>>>(xh, Wqkv_t, nullptr, Qb, Kb, Vb,
                                          8192, 1536, 1024);
  // V -> V^T (xh space is dead now)
  transpose_v_kernel<<<dim3(64, 16), 256, 0, stream>>>(Vb, Vt, 4096);
  // attention (512 blocks, XCD-decoded inside)
  attn_kernel<<<512, 512, 0, stream>>>(Qb, Kb, Vt, At, 4096);
  // output projection: [8192 x 1024 x 512]  (512 = 64x * 8y)
  gemm_kernel<0><<<512, 256, 0, stream>>>(At, Wo_t, out, nullptr, nullptr, nullptr,
                                          8192, 1024, 512);
}

// Round 6
// 163.358 us; speedup vs baseline: 1.1740x; 1.0418x over previous
//
#include <hip/hip_runtime.h>

// ---------------------------------------------------------------------------
// FlashAttention_45844480917693 — cosine-sim attention, MI355X (gfx950)
// R6: softmax VALU work moved into MFMA pipe — Q pre-scaled by 16*log2e in
// QKV epilogue, exp bias folded into QK accumulator init (C-operand), rowsum
// computed by a ones-B MFMA alongside PV. Keeps R4's KVBLK=128, XCD-local
// head mapping, setprio, double-buffered K/V, swapped QK^T, packed P.
// ---------------------------------------------------------------------------

typedef _Float16 f16;
typedef _Float16 f16x4 __attribute__((ext_vector_type(4)));
typedef _Float16 f16x8 __attribute__((ext_vector_type(8)));
typedef float f32x4 __attribute__((ext_vector_type(4)));

#define MFMA_F16(a, b, c) __builtin_amdgcn_mfma_f32_16x16x32_f16((a), (b), (c), 0, 0, 0)

// 16 * log2(e)
#define QSCALE 23.083120654223414f
// exp2 bias: -QSCALE + 14 (P pre-scaled by 2^14, cancels in rowsum division)
#define EXPBIAS -9.083120654223414f

__device__ __forceinline__ void gl_lds16(const void* g, void* l) {
  // async global->LDS, 16B per lane; LDS dest = wave-uniform base + lane*16
  __builtin_amdgcn_global_load_lds(
      (const __attribute__((address_space(1))) void*)g,
      (__attribute__((address_space(3))) void*)l, 16, 0, 0);
}

// ---------------------------------------------------------------------------
// x (fp32) -> fp16, 8 elements/thread
__global__ void convert_x_kernel(const float* __restrict__ x, f16* __restrict__ xh, int n8) {
  int i = blockIdx.x * 256 + threadIdx.x;
  if (i >= n8) return;
  const float4* xv = (const float4*)x;
  float4 a = xv[2 * i], b = xv[2 * i + 1];
  f16x8 o;
  o[0] = (f16)a.x; o[1] = (f16)a.y; o[2] = (f16)a.z; o[3] = (f16)a.w;
  o[4] = (f16)b.x; o[5] = (f16)b.y; o[6] = (f16)b.z; o[7] = (f16)b.w;
  ((f16x8*)xh)[i] = o;
}

// W [K][ldw] fp32, take cols [col0, col0+gridDim.x*64) -> out[c][k] fp16 ([out][in])
__global__ void transpose_w_kernel(const float* __restrict__ W, int ldw, int col0,
                                   int K, f16* __restrict__ out) {
  __shared__ float t[64][65];
  int tx = threadIdx.x, ty = threadIdx.y;
  int c0 = blockIdx.x * 64, k0 = blockIdx.y * 64;
#pragma unroll
  for (int i = 0; i < 8; i++)
    t[ty + i * 8][tx] = W[(long)(k0 + ty + i * 8) * ldw + col0 + c0 + tx];
  __syncthreads();
#pragma unroll
  for (int i = 0; i < 8; i++)
    out[(long)(c0 + ty + i * 8) * K + k0 + tx] = (f16)t[tx][ty + i * 8];
}

// Vb [bh][n][64] -> Vt [bh][64][n], 64x64 f16 tiles, swizzled LDS
__global__ void transpose_v_kernel(const f16* __restrict__ Vb, f16* __restrict__ Vt, int n) {
  __shared__ f16 t[64 * 64];
  const int tid = threadIdx.x;
  const int bh = blockIdx.y;
  const int n0 = blockIdx.x * 64;
  const f16* src = Vb + ((long)bh * n + n0) * 64;
  const int j = tid >> 3, c = tid & 7;
  f16x8 v0 = *(const f16x8*)(src + j * 64 + c * 8);
  f16x8 v1 = *(const f16x8*)(src + (j + 32) * 64 + c * 8);
  *(f16x8*)(&t[j * 64 + ((c ^ (j & 7)) << 3)]) = v0;
  *(f16x8*)(&t[(j + 32) * 64 + ((c ^ (j & 7)) << 3)]) = v1;  // (j+32)&7 == j&7
  __syncthreads();
  const int d = tid >> 3, cj = tid & 7;
  f16x8 o0, o1;
#pragma unroll
  for (int e = 0; e < 8; e++) {
    int jj = cj * 8 + e;
    o0[e] = t[jj * 64 + (((d >> 3) ^ (jj & 7)) << 3) + (d & 7)];
    o1[e] = t[jj * 64 + ((((d + 32) >> 3) ^ (jj & 7)) << 3) + ((d + 32) & 7)];
  }
  *(f16x8*)(Vt + ((long)bh * 64 + d) * n + n0 + cj * 8) = o0;
  *(f16x8*)(Vt + ((long)bh * 64 + d + 32) * n + n0 + cj * 8) = o1;
}

// ---------------------------------------------------------------------------
// GEMM: C[M][N] = A[M][K] * Bt[N][K]^T, 128x128 tile, BK=32, 4 waves (2x2),
// MODE 0: fp32 C out. MODE 1: fused QKV epilogue (l2norm for Q/K; Q also
// pre-scaled by 16*log2e for the attn exp2 fold).
// 1-D grid, XCD-aware decode: x-panels grouped per XCD (A chunk L2-resident).
template <int MODE>
__global__ __launch_bounds__(256, 2)
void gemm_kernel(const f16* __restrict__ A, const f16* __restrict__ Bt,
                 float* __restrict__ C,
                 f16* __restrict__ Qb, f16* __restrict__ Kb, f16* __restrict__ Vb,
                 int M, int N, int K) {
  __shared__ f16 As[128 * 32];
  __shared__ f16 Bs[128 * 32];
  const int tid = threadIdx.x;
  const int lane = tid & 63;
  const int wid = tid >> 6;
  const int wr = wid >> 1, wc = wid & 1;
  const int lr = lane & 15, lk = lane >> 4;
  const int lin = blockIdx.x;
  const int bx = ((lin & 7) << 3) | ((lin >> 3) & 7);  // XCD (lin%8) owns 8 x-panels
  const int by = lin >> 6;
  const long m0 = (long)bx * 128;
  const int n0 = by * 128;

  f32x4 acc[4][4] = {};

  const int c0 = tid, c1 = tid + 256;
  const int ar0 = c0 >> 2, ah0 = (c0 & 3) ^ ((ar0 >> 1) & 3);
  const int ar1 = c1 >> 2, ah1 = (c1 & 3) ^ ((ar1 >> 1) & 3);
  const f16* pa0 = A + (m0 + ar0) * K + ah0 * 8;
  const f16* pa1 = A + (m0 + ar1) * K + ah1 * 8;
  const f16* pb0 = Bt + (long)(n0 + ar0) * K + ah0 * 8;
  const f16* pb1 = Bt + (long)(n0 + ar1) * K + ah1 * 8;

  for (int k0 = 0; k0 < K; k0 += 32) {
    __syncthreads();
    gl_lds16(pa0 + k0, As + c0 * 8);
    gl_lds16(pa1 + k0, As + c1 * 8);
    gl_lds16(pb0 + k0, Bs + c0 * 8);
    gl_lds16(pb1 + k0, Bs + c1 * 8);
    __syncthreads();

    f16x8 af[4], bf[4];
#pragma unroll
    for (int mi = 0; mi < 4; mi++) {
      int row = wr * 64 + mi * 16 + lr;
      int ch = lk ^ ((row >> 1) & 3);
      af[mi] = *(const f16x8*)(As + row * 32 + ch * 8);
    }
#pragma unroll
    for (int ni = 0; ni < 4; ni++) {
      int row = wc * 64 + ni * 16 + lr;
      int ch = lk ^ ((row >> 1) & 3);
      bf[ni] = *(const f16x8*)(Bs + row * 32 + ch * 8);
    }
    __builtin_amdgcn_s_setprio(1);
#pragma unroll
    for (int mi = 0; mi < 4; mi++)
#pragma unroll
      for (int ni = 0; ni < 4; ni++)
        acc[mi][ni] = MFMA_F16(af[mi], bf[ni], acc[mi][ni]);
    __builtin_amdgcn_s_setprio(0);
  }

  if (MODE == 0) {
#pragma unroll
    for (int mi = 0; mi < 4; mi++) {
      long mrow = m0 + wr * 64 + mi * 16 + lk * 4;
#pragma unroll
      for (int r = 0; r < 4; r++)
#pragma unroll
        for (int ni = 0; ni < 4; ni++)
          C[(mrow + r) * N + n0 + wc * 64 + ni * 16 + lr] = acc[mi][ni][r];
    }
  } else {
    const int region = by >> 2;                      // 0=Q, 1=K, 2=V
    const int head = (by & 3) * 2 + wc;
    f16* buf = (region == 0) ? Qb : ((region == 1) ? Kb : Vb);
    const float nscale = (region == 0) ? QSCALE : 1.f;  // Q pre-scaled
#pragma unroll
    for (int mi = 0; mi < 4; mi++) {
      float scl[4];
      if (region < 2) {
#pragma unroll
        for (int r = 0; r < 4; r++) {
          float s2 = 0.f;
#pragma unroll
          for (int ni = 0; ni < 4; ni++) s2 += acc[mi][ni][r] * acc[mi][ni][r];
          s2 += __shfl_xor(s2, 1);
          s2 += __shfl_xor(s2, 2);
          s2 += __shfl_xor(s2, 4);
          s2 += __shfl_xor(s2, 8);
          scl[r] = nscale / fmaxf(sqrtf(s2), 1e-12f);
        }
      } else {
#pragma unroll
        for (int r = 0; r < 4; r++) scl[r] = 1.f;
      }
#pragma unroll
      for (int r = 0; r < 4; r++) {
        int m = (int)m0 + wr * 64 + mi * 16 + lk * 4 + r;
        int bb = m >> 12, nn = m & 4095;
        f16* dst = buf + (((long)(bb * 8 + head) * 4096 + nn) << 6);
#pragma unroll
        for (int ni = 0; ni < 4; ni++)
          dst[ni * 16 + lr] = (f16)(acc[mi][ni][r] * scl[r]);
      }
    }
  }
}

// ---------------------------------------------------------------------------
// Attention v5. 1-D grid of 512; decode bh = (lin&7)|((lin>>8)<<3) so each
// XCD owns 2 heads (K+V = 2MB -> L2-resident). 8 waves x 16 q-rows.
// KVBLK=128, double-buffered, prefetch before compute, one barrier/tile.
// Softmax folded into MFMA: Q pre-scaled by 16*log2e, QK acc init = EXPBIAS
// (so p = exp2(acc) raw), rowsum via ones-B MFMA alongside PV.
__global__ __launch_bounds__(512, 4)
void attn_kernel(const f16* __restrict__ Qb, const f16* __restrict__ Kb,
                 const f16* __restrict__ Vt, f16* __restrict__ Ob, int n) {
  __shared__ f16 Ks[2][128 * 64];    // [j][d], 16B-chunk ^= (j&7)       16KB x2
  __shared__ f16 Vs[2][64 * 128];    // [d][j], 16B-chunk ^= (d&15)      16KB x2
  __shared__ f16 Ps[8][16 * 64];     // per-wave [q][j], chunk ^= (q&7)  16KB
  const int tid = threadIdx.x, lane = tid & 63, wid = tid >> 6;
  const int lr = lane & 15, lk = lane >> 4;
  const int lin = blockIdx.x;
  const int bh = (lin & 7) | ((lin >> 8) << 3);
  const int qx = (lin >> 3) & 31;
  const long nl = n;
  const f16* Qg = Qb + (long)bh * nl * 64;
  const f16* Kg = Kb + (long)bh * nl * 64;
  const f16* Vg = Vt + (long)bh * 64 * nl;
  const int q0 = qx * 128 + wid * 16;

  // Q fragments (B-operand of swapped QK^T): col q = lr, k d = kc*32+lk*8+e
  f16x8 qf[2];
#pragma unroll
  for (int kc = 0; kc < 2; kc++)
    qf[kc] = *(const f16x8*)(Qg + (long)(q0 + lr) * 64 + kc * 32 + lk * 8);

  // staging: dst is always lds_base + tid*8 (+4096 for 2nd pass); source
  // pre-swizzled so LDS stays lane-linear.
  const int krow = tid >> 3;                          // 0..63 (+64 2nd pass)
  const int kcol = ((tid & 7) ^ (krow & 7)) * 8;
  const int vrow = tid >> 4;                          // 0..31 (+32 2nd pass)
  const int vcol = ((tid & 15) ^ (vrow & 15)) * 8;

  f32x4 oacc[4] = {};
  f32x4 osum = {0.f, 0.f, 0.f, 0.f};                  // rowsum accumulator
  const f32x4 initv = {EXPBIAS, EXPBIAS, EXPBIAS, EXPBIAS};
  f16x8 ones;
#pragma unroll
  for (int e = 0; e < 8; e++) ones[e] = (f16)1.f;

  // prologue: stage tile 0 into buf 0
  gl_lds16(Kg + (long)krow * 64 + kcol, &Ks[0][tid * 8]);
  gl_lds16(Kg + (long)(krow + 64) * 64 + kcol, &Ks[0][tid * 8 + 4096]);
  gl_lds16(Vg + (long)vrow * nl + vcol, &Vs[0][tid * 8]);
  gl_lds16(Vg + (long)(vrow + 32) * nl + vcol, &Vs[0][tid * 8 + 4096]);
  __syncthreads();

  const int nt = n >> 7;
  for (int t = 0; t < nt; t++) {
    const int cur = t & 1;
    // prefetch tile t+1 — overlaps ALL of compute(t)
    if (t + 1 < nt) {
      const long j0 = (long)(t + 1) << 7;
      gl_lds16(Kg + (j0 + krow) * 64 + kcol, &Ks[cur ^ 1][tid * 8]);
      gl_lds16(Kg + (j0 + krow + 64) * 64 + kcol, &Ks[cur ^ 1][tid * 8 + 4096]);
      gl_lds16(Vg + (long)vrow * nl + j0 + vcol, &Vs[cur ^ 1][tid * 8]);
      gl_lds16(Vg + (long)(vrow + 32) * nl + j0 + vcol, &Vs[cur ^ 1][tid * 8 + 4096]);
    }

    // S^T = K * Q^T over all 128 j: rows j (regs), cols q (lanes).
    // Accumulator seeded with EXPBIAS so p = exp2(acc) directly.
    f32x4 s[8];
    __builtin_amdgcn_s_setprio(1);
#pragma unroll
    for (int jt = 0; jt < 8; jt++) {
      const int j = jt * 16 + lr;
      const f16x8 kf0 = *(const f16x8*)(&Ks[cur][j * 64 + ((lk ^ (j & 7)) << 3)]);
      const f16x8 kf1 = *(const f16x8*)(&Ks[cur][j * 64 + (((4 + lk) ^ (j & 7)) << 3)]);
      f32x4 acc0 = MFMA_F16(kf0, qf[0], initv);
      s[jt] = MFMA_F16(kf1, qf[1], acc0);
    }
    __builtin_amdgcn_s_setprio(0);

    // two 64-j sub-tiles: p = exp2(s) -> Ps -> PV + ones-MFMA rowsum
#pragma unroll
    for (int sub = 0; sub < 2; sub++) {
#pragma unroll
      for (int jt2 = 0; jt2 < 4; jt2++) {
        const f32x4 sv = s[sub * 4 + jt2];
        const float p0 = __builtin_amdgcn_exp2f(sv[0]);
        const float p1 = __builtin_amdgcn_exp2f(sv[1]);
        const float p2 = __builtin_amdgcn_exp2f(sv[2]);
        const float p3 = __builtin_amdgcn_exp2f(sv[3]);
        const auto h01 = __builtin_amdgcn_cvt_pkrtz(p0, p1);
        const auto h23 = __builtin_amdgcn_cvt_pkrtz(p2, p3);
        f16x4 pk;
        pk[0] = h01[0]; pk[1] = h01[1]; pk[2] = h23[0]; pk[3] = h23[1];
        const int c16 = jt2 * 2 + (lk >> 1);
        *(f16x4*)(&Ps[wid][lr * 64 + ((c16 ^ (lr & 7)) << 3) + ((lk & 1) << 2)]) = pk;
      }

      __builtin_amdgcn_s_setprio(1);
#pragma unroll
      for (int kc2 = 0; kc2 < 2; kc2++) {
        const int c16 = kc2 * 4 + lk;
        const f16x8 pa = *(const f16x8*)(&Ps[wid][lr * 64 + ((c16 ^ (lr & 7)) << 3)]);
        f16x8 vf[4];
#pragma unroll
        for (int dt = 0; dt < 4; dt++) {
          const int d = dt * 16 + lr;
          vf[dt] = *(const f16x8*)(&Vs[cur][d * 128 + (((sub * 8 + kc2 * 4 + lk) ^ (d & 15)) << 3)]);
        }
        osum = MFMA_F16(pa, ones, osum);              // rowsum in MFMA pipe
#pragma unroll
        for (int dt = 0; dt < 4; dt++)
          oacc[dt] = MFMA_F16(pa, vf[dt], oacc[dt]);
      }
      __builtin_amdgcn_s_setprio(0);
    }

    __syncthreads();  // drains prefetch vmcnt + all waves done with buf[cur]
  }

  // osum[r] = rowsum for q-row lk*4+r (duplicated across the 16 lr cols)
  const int bb = bh >> 3, hh = bh & 7;
#pragma unroll
  for (int r = 0; r < 4; r++) {
    const float inv = 1.f / fmaxf(osum[r], 0.016384f);   // 1e-6 * 2^14
    const int qq = q0 + lk * 4 + r;
    f16* dst = Ob + (((long)(bb * 4096 + qq)) << 9) + hh * 64;
#pragma unroll
    for (int dt = 0; dt < 4; dt++)
      dst[dt * 16 + lr] = (f16)(oacc[dt][r] * inv);
  }
}

// ---------------------------------------------------------------------------
extern "C" void kernel_launch(void* const* d_in, const int* in_sizes, int n_in,
                              void* d_out, int out_size, void* d_ws, size_t ws_size,
                              hipStream_t stream) {
  const float* x   = (const float*)d_in[0];   // [2,4096,1024]
  const float* Wq  = (const float*)d_in[1];   // [1024,512]
  const float* Wkv = (const float*)d_in[2];   // [1024,1024]
  const float* Wo  = (const float*)d_in[3];   // [512,1024]
  float* out = (float*)d_out;                 // [2,4096,1024] fp32

  char* ws = (char*)d_ws;
  f16* xh     = (f16*)(ws);                   // 16.78 MB  [8192][1024]; reused as Vt after QKV GEMM
  f16* Wqkv_t = (f16*)(ws + 16777216);        //  3.15 MB  [1536][1024]
  f16* Wo_t   = (f16*)(ws + 19922944);        //  1.05 MB  [1024][512]
  f16* Qb     = (f16*)(ws + 20971520);        //  8.39 MB  [16][4096][64]
  f16* Kb     = (f16*)(ws + 29360128);        //  8.39 MB
  f16* Vb     = (f16*)(ws + 37748736);        //  8.39 MB
  f16* At     = (f16*)(ws + 46137344);        //  8.39 MB  [8192][512]
  f16* Vt     = xh;                           //  8.39 MB  [16][64][4096] (xh dead after QKV GEMM)

  convert_x_kernel<<<4096, 256, 0, stream>>>(x, xh, 1048576);

  dim3 tb(64, 8);
  transpose_w_kernel<<<dim3(8, 16), tb, 0, stream>>>(Wq, 512, 0, 1024, Wqkv_t);
  transpose_w_kernel<<<dim3(8, 16), tb, 0, stream>>>(Wkv, 1024, 0, 1024, Wqkv_t + 512 * 1024);
  transpose_w_kernel<<<dim3(8, 16), tb, 0, stream>>>(Wkv, 1024, 512, 1024, Wqkv_t + 1024 * 1024);
  transpose_w_kernel<<<dim3(16, 8), tb, 0, stream>>>(Wo, 1024, 0, 512, Wo_t);

  // fused QKV projection + l2norm (+Q prescale): [8192 x 1536 x 1024]
  gemm_kernel<1><<<768, 256, 0, stream>>>(xh, Wqkv_t, nullptr, Qb, Kb, Vb,
                                          8192, 1536, 1024);
  // V -> V^T (xh space is dead now)
  transpose_v_kernel<<<dim3(64, 16), 256, 0, stream>>>(Vb, Vt, 4096);
  // attention (512 blocks, XCD-decoded inside)
  attn_kernel<<<512, 512, 0, stream>>>(Qb, Kb, Vt, At, 4096);
  // output projection: [8192 x 1024 x 512]
  gemm_kernel<0><<<512, 256, 0, stream>>>(At, Wo_t, out, nullptr, nullptr, nullptr,
                                          8192, 1024, 512);
}

// Round 7
// 161.965 us; speedup vs baseline: 1.1841x; 1.0086x over previous
//
#include <hip/hip_runtime.h>

// ---------------------------------------------------------------------------
// FlashAttention_45844480917693 — cosine-sim attention, MI355X (gfx950)
// R7: attn rewritten on 32x32x16 MFMA, 4 waves x 32 q. LDS traffic per FLOP
// halved (K/V tile reads amortized over 2x q). P stays fully in registers:
// swapped QK^T 32x32 D-layout -> v_permlane32_swap rebuilds PV A-fragments;
// rowsum via v_fdot2 on packed P words. Keeps KVBLK=128, XCD-local heads,
// double-buffered K/V, softmax folded into MFMA C-init.
// ---------------------------------------------------------------------------

typedef _Float16 f16;
typedef _Float16 f16x4 __attribute__((ext_vector_type(4)));
typedef _Float16 f16x8 __attribute__((ext_vector_type(8)));
typedef float f32x4 __attribute__((ext_vector_type(4)));
typedef float f32x16 __attribute__((ext_vector_type(16)));
typedef int i32x4 __attribute__((ext_vector_type(4)));

#define MFMA_F16(a, b, c) __builtin_amdgcn_mfma_f32_16x16x32_f16((a), (b), (c), 0, 0, 0)
#define MFMA32(a, b, c) __builtin_amdgcn_mfma_f32_32x32x16_f16((a), (b), (c), 0, 0, 0)

// 16 * log2(e)
#define QSCALE 23.083120654223414f
// exp2 bias: -QSCALE + 14 (P pre-scaled by 2^14, cancels in rowsum division)
#define EXPBIAS -9.083120654223414f

__device__ __forceinline__ void gl_lds16(const void* g, void* l) {
  // async global->LDS, 16B per lane; LDS dest = wave-uniform base + lane*16
  __builtin_amdgcn_global_load_lds(
      (const __attribute__((address_space(1))) void*)g,
      (__attribute__((address_space(3))) void*)l, 16, 0, 0);
}

// ---------------------------------------------------------------------------
// x (fp32) -> fp16, 8 elements/thread
__global__ void convert_x_kernel(const float* __restrict__ x, f16* __restrict__ xh, int n8) {
  int i = blockIdx.x * 256 + threadIdx.x;
  if (i >= n8) return;
  const float4* xv = (const float4*)x;
  float4 a = xv[2 * i], b = xv[2 * i + 1];
  f16x8 o;
  o[0] = (f16)a.x; o[1] = (f16)a.y; o[2] = (f16)a.z; o[3] = (f16)a.w;
  o[4] = (f16)b.x; o[5] = (f16)b.y; o[6] = (f16)b.z; o[7] = (f16)b.w;
  ((f16x8*)xh)[i] = o;
}

// W [K][ldw] fp32, take cols [col0, col0+gridDim.x*64) -> out[c][k] fp16 ([out][in])
__global__ void transpose_w_kernel(const float* __restrict__ W, int ldw, int col0,
                                   int K, f16* __restrict__ out) {
  __shared__ float t[64][65];
  int tx = threadIdx.x, ty = threadIdx.y;
  int c0 = blockIdx.x * 64, k0 = blockIdx.y * 64;
#pragma unroll
  for (int i = 0; i < 8; i++)
    t[ty + i * 8][tx] = W[(long)(k0 + ty + i * 8) * ldw + col0 + c0 + tx];
  __syncthreads();
#pragma unroll
  for (int i = 0; i < 8; i++)
    out[(long)(c0 + ty + i * 8) * K + k0 + tx] = (f16)t[tx][ty + i * 8];
}

// Vb [bh][n][64] -> Vt [bh][64][n], 64x64 f16 tiles, swizzled LDS
__global__ void transpose_v_kernel(const f16* __restrict__ Vb, f16* __restrict__ Vt, int n) {
  __shared__ f16 t[64 * 64];
  const int tid = threadIdx.x;
  const int bh = blockIdx.y;
  const int n0 = blockIdx.x * 64;
  const f16* src = Vb + ((long)bh * n + n0) * 64;
  const int j = tid >> 3, c = tid & 7;
  f16x8 v0 = *(const f16x8*)(src + j * 64 + c * 8);
  f16x8 v1 = *(const f16x8*)(src + (j + 32) * 64 + c * 8);
  *(f16x8*)(&t[j * 64 + ((c ^ (j & 7)) << 3)]) = v0;
  *(f16x8*)(&t[(j + 32) * 64 + ((c ^ (j & 7)) << 3)]) = v1;  // (j+32)&7 == j&7
  __syncthreads();
  const int d = tid >> 3, cj = tid & 7;
  f16x8 o0, o1;
#pragma unroll
  for (int e = 0; e < 8; e++) {
    int jj = cj * 8 + e;
    o0[e] = t[jj * 64 + (((d >> 3) ^ (jj & 7)) << 3) + (d & 7)];
    o1[e] = t[jj * 64 + ((((d + 32) >> 3) ^ (jj & 7)) << 3) + ((d + 32) & 7)];
  }
  *(f16x8*)(Vt + ((long)bh * 64 + d) * n + n0 + cj * 8) = o0;
  *(f16x8*)(Vt + ((long)bh * 64 + d + 32) * n + n0 + cj * 8) = o1;
}

// ---------------------------------------------------------------------------
// GEMM: C[M][N] = A[M][K] * Bt[N][K]^T, 128x128 tile, BK=32, 4 waves (2x2),
// MODE 0: fp32 C out. MODE 1: fused QKV epilogue (l2norm for Q/K; Q also
// pre-scaled by 16*log2e for the attn exp2 fold).
template <int MODE>
__global__ __launch_bounds__(256, 2)
void gemm_kernel(const f16* __restrict__ A, const f16* __restrict__ Bt,
                 float* __restrict__ C,
                 f16* __restrict__ Qb, f16* __restrict__ Kb, f16* __restrict__ Vb,
                 int M, int N, int K) {
  __shared__ f16 As[128 * 32];
  __shared__ f16 Bs[128 * 32];
  const int tid = threadIdx.x;
  const int lane = tid & 63;
  const int wid = tid >> 6;
  const int wr = wid >> 1, wc = wid & 1;
  const int lr = lane & 15, lk = lane >> 4;
  const int lin = blockIdx.x;
  const int bx = ((lin & 7) << 3) | ((lin >> 3) & 7);  // XCD (lin%8) owns 8 x-panels
  const int by = lin >> 6;
  const long m0 = (long)bx * 128;
  const int n0 = by * 128;

  f32x4 acc[4][4] = {};

  const int c0 = tid, c1 = tid + 256;
  const int ar0 = c0 >> 2, ah0 = (c0 & 3) ^ ((ar0 >> 1) & 3);
  const int ar1 = c1 >> 2, ah1 = (c1 & 3) ^ ((ar1 >> 1) & 3);
  const f16* pa0 = A + (m0 + ar0) * K + ah0 * 8;
  const f16* pa1 = A + (m0 + ar1) * K + ah1 * 8;
  const f16* pb0 = Bt + (long)(n0 + ar0) * K + ah0 * 8;
  const f16* pb1 = Bt + (long)(n0 + ar1) * K + ah1 * 8;

  for (int k0 = 0; k0 < K; k0 += 32) {
    __syncthreads();
    gl_lds16(pa0 + k0, As + c0 * 8);
    gl_lds16(pa1 + k0, As + c1 * 8);
    gl_lds16(pb0 + k0, Bs + c0 * 8);
    gl_lds16(pb1 + k0, Bs + c1 * 8);
    __syncthreads();

    f16x8 af[4], bf[4];
#pragma unroll
    for (int mi = 0; mi < 4; mi++) {
      int row = wr * 64 + mi * 16 + lr;
      int ch = lk ^ ((row >> 1) & 3);
      af[mi] = *(const f16x8*)(As + row * 32 + ch * 8);
    }
#pragma unroll
    for (int ni = 0; ni < 4; ni++) {
      int row = wc * 64 + ni * 16 + lr;
      int ch = lk ^ ((row >> 1) & 3);
      bf[ni] = *(const f16x8*)(Bs + row * 32 + ch * 8);
    }
    __builtin_amdgcn_s_setprio(1);
#pragma unroll
    for (int mi = 0; mi < 4; mi++)
#pragma unroll
      for (int ni = 0; ni < 4; ni++)
        acc[mi][ni] = MFMA_F16(af[mi], bf[ni], acc[mi][ni]);
    __builtin_amdgcn_s_setprio(0);
  }

  if (MODE == 0) {
#pragma unroll
    for (int mi = 0; mi < 4; mi++) {
      long mrow = m0 + wr * 64 + mi * 16 + lk * 4;
#pragma unroll
      for (int r = 0; r < 4; r++)
#pragma unroll
        for (int ni = 0; ni < 4; ni++)
          C[(mrow + r) * N + n0 + wc * 64 + ni * 16 + lr] = acc[mi][ni][r];
    }
  } else {
    const int region = by >> 2;                      // 0=Q, 1=K, 2=V
    const int head = (by & 3) * 2 + wc;
    f16* buf = (region == 0) ? Qb : ((region == 1) ? Kb : Vb);
    const float nscale = (region == 0) ? QSCALE : 1.f;  // Q pre-scaled
#pragma unroll
    for (int mi = 0; mi < 4; mi++) {
      float scl[4];
      if (region < 2) {
#pragma unroll
        for (int r = 0; r < 4; r++) {
          float s2 = 0.f;
#pragma unroll
          for (int ni = 0; ni < 4; ni++) s2 += acc[mi][ni][r] * acc[mi][ni][r];
          s2 += __shfl_xor(s2, 1);
          s2 += __shfl_xor(s2, 2);
          s2 += __shfl_xor(s2, 4);
          s2 += __shfl_xor(s2, 8);
          scl[r] = nscale / fmaxf(sqrtf(s2), 1e-12f);
        }
      } else {
#pragma unroll
        for (int r = 0; r < 4; r++) scl[r] = 1.f;
      }
#pragma unroll
      for (int r = 0; r < 4; r++) {
        int m = (int)m0 + wr * 64 + mi * 16 + lk * 4 + r;
        int bb = m >> 12, nn = m & 4095;
        f16* dst = buf + (((long)(bb * 8 + head) * 4096 + nn) << 6);
#pragma unroll
        for (int ni = 0; ni < 4; ni++)
          dst[ni * 16 + lr] = (f16)(acc[mi][ni][r] * scl[r]);
      }
    }
  }
}

// ---------------------------------------------------------------------------
// Attention v6: 32x32x16 MFMA, 4 waves x 32 q (256 threads), KVBLK=128.
// Swapped QK^T (A=K j-rows, B=Q q-cols): D gives q=lane&31, j_local=
// (r&3)+8*(r>>2)+4*(lane>>5). PV A-fragment rebuilt IN REGISTERS from packed
// P words via v_permlane32_swap (swap(w0,w2)->words 0/2, swap(w1,w3)->1/3).
// Rowsum via v_fdot2 on packed words + one shfl_xor(32) at the end.
// K/V double-buffered in LDS (64 KB), prefetch before compute.
__global__ __launch_bounds__(256, 2)
void attn_kernel(const f16* __restrict__ Qb, const f16* __restrict__ Kb,
                 const f16* __restrict__ Vt, f16* __restrict__ Ob, int n) {
  __shared__ f16 Ks[2][128 * 64];    // [j][d], 16B-chunk ^= (j&7)   16KB x2
  __shared__ f16 Vs[2][64 * 128];    // [d][j], 16B-chunk ^= (d&15)  16KB x2
  const int tid = threadIdx.x, lane = tid & 63, wid = tid >> 6;  // wid 0..3
  const int ql = lane & 31, hi = lane >> 5;
  const int lin = blockIdx.x;
  const int bh = (lin & 7) | ((lin >> 8) << 3);
  const int qx = (lin >> 3) & 31;
  const long nl = n;
  const f16* Qg = Qb + (long)bh * nl * 64;
  const f16* Kg = Kb + (long)bh * nl * 64;
  const f16* Vg = Vt + (long)bh * 64 * nl;
  const int q0w = qx * 128 + wid * 32;

  // Q fragments (B-operand): col q = ql, k d = kc*16 + hi*8 + e
  f16x8 qf[4];
#pragma unroll
  for (int kc = 0; kc < 4; kc++)
    qf[kc] = *(const f16x8*)(Qg + (long)(q0w + ql) * 64 + kc * 16 + hi * 8);

  // staging source offsets (4 K-chunks + 4 V-chunks per thread per tile);
  // LDS dest stays lane-linear, source pre-swizzled.
  int ksrc[4], vsrc[4];
#pragma unroll
  for (int p = 0; p < 4; p++) {
    const int ci = tid + p * 256;
    const int kj = ci >> 3, kc_ = ci & 7;
    ksrc[p] = kj * 64 + ((kc_ ^ (kj & 7)) << 3);
    const int vd = ci >> 4, vc = ci & 15;
    vsrc[p] = vd * n + ((vc ^ (vd & 15)) << 3);
  }

  f32x16 oacc[2][2] = {};   // [kb parity][dt] — 4 independent MFMA chains
  float rsum = 0.f;
  f32x16 initv;
#pragma unroll
  for (int e = 0; e < 16; e++) initv[e] = EXPBIAS;
  const auto one2 = __builtin_amdgcn_cvt_pkrtz(1.f, 1.f);

  // prologue: stage tile 0 into buf 0
#pragma unroll
  for (int p = 0; p < 4; p++) {
    gl_lds16(Kg + ksrc[p], &Ks[0][(tid + p * 256) * 8]);
    gl_lds16(Vg + vsrc[p], &Vs[0][(tid + p * 256) * 8]);
  }
  __syncthreads();

  const int nt = n >> 7;
  for (int t = 0; t < nt; t++) {
    const int cur = t & 1;
    if (t + 1 < nt) {
      const long kadv = (long)(t + 1) * 8192;   // 128 rows * 64 d
      const long vadv = (long)(t + 1) * 128;    // +128 j
#pragma unroll
      for (int p = 0; p < 4; p++) {
        gl_lds16(Kg + kadv + ksrc[p], &Ks[cur ^ 1][(tid + p * 256) * 8]);
        gl_lds16(Vg + vadv + vsrc[p], &Vs[cur ^ 1][(tid + p * 256) * 8]);
      }
    }

    // QK: S^T[j][q], 16 MFMA; C-init = EXPBIAS so p = exp2(s) directly
    f32x16 s[4];
    __builtin_amdgcn_s_setprio(1);
#pragma unroll
    for (int jt = 0; jt < 4; jt++) {
      const int j = jt * 32 + ql;
      const int sw = j & 7;
      const f16x8 k0 = *(const f16x8*)(&Ks[cur][j * 64 + ((hi ^ sw) << 3)]);
      s[jt] = MFMA32(k0, qf[0], initv);
#pragma unroll
      for (int kc = 1; kc < 4; kc++) {
        const f16x8 kf = *(const f16x8*)(&Ks[cur][j * 64 + ((((kc << 1) | hi) ^ sw) << 3)]);
        s[jt] = MFMA32(kf, qf[kc], s[jt]);
      }
    }
    __builtin_amdgcn_s_setprio(0);

    // per 32-j tile: exp2 -> pack -> fdot2 rowsum -> permlane -> PV
#pragma unroll
    for (int jt = 0; jt < 4; jt++) {
      int w[8];
#pragma unroll
      for (int m = 0; m < 8; m++) {
        const float pa = __builtin_amdgcn_exp2f(s[jt][2 * m]);
        const float pb = __builtin_amdgcn_exp2f(s[jt][2 * m + 1]);
        const auto h = __builtin_amdgcn_cvt_pkrtz(pa, pb);
        rsum = __builtin_amdgcn_fdot2(h, one2, rsum, false);
        w[m] = __builtin_bit_cast(int, h);
      }
#pragma unroll
      for (int kl = 0; kl < 2; kl++) {
        int a0 = w[4 * kl + 0], a1 = w[4 * kl + 1];
        int a2 = w[4 * kl + 2], a3 = w[4 * kl + 3];
        // v_permlane32_swap: dst.hi32lanes <-> src.lo32lanes
        asm volatile("v_permlane32_swap_b32 %0, %1" : "+v"(a0), "+v"(a2));
        asm volatile("v_permlane32_swap_b32 %0, %1" : "+v"(a1), "+v"(a3));
        i32x4 fi = {a0, a1, a2, a3};
        const f16x8 pfrag = __builtin_bit_cast(f16x8, fi);
        const int kb = jt * 2 + kl;
        __builtin_amdgcn_s_setprio(1);
#pragma unroll
        for (int dt = 0; dt < 2; dt++) {
          const int d = dt * 32 + ql;
          const f16x8 vf =
              *(const f16x8*)(&Vs[cur][d * 128 + ((((kb << 1) | hi) ^ (d & 15)) << 3)]);
          oacc[kl][dt] = MFMA32(pfrag, vf, oacc[kl][dt]);
        }
        __builtin_amdgcn_s_setprio(0);
      }
    }

    __syncthreads();  // drains prefetch vmcnt + all waves done with buf[cur]
  }

  // final rowsum (other hi-half holds complementary j's), divide, store
  rsum += __shfl_xor(rsum, 32);
  const int bb = bh >> 3, hh = bh & 7;
#pragma unroll
  for (int r = 0; r < 16; r++) {
    const int qloc = (r & 3) + 8 * (r >> 2) + 4 * hi;
    const float sm = __shfl(rsum, qloc);                // rowsum for q0w+qloc
    const float inv = 1.f / fmaxf(sm, 0.016384f);       // 1e-6 * 2^14
    f16* dst = Ob + (((long)(bb * 4096 + q0w + qloc)) << 9) + hh * 64;
    dst[ql] = (f16)((oacc[0][0][r] + oacc[1][0][r]) * inv);
    dst[32 + ql] = (f16)((oacc[0][1][r] + oacc[1][1][r]) * inv);
  }
}

// ---------------------------------------------------------------------------
extern "C" void kernel_launch(void* const* d_in, const int* in_sizes, int n_in,
                              void* d_out, int out_size, void* d_ws, size_t ws_size,
                              hipStream_t stream) {
  const float* x   = (const float*)d_in[0];   // [2,4096,1024]
  const float* Wq  = (const float*)d_in[1];   // [1024,512]
  const float* Wkv = (const float*)d_in[2];   // [1024,1024]
  const float* Wo  = (const float*)d_in[3];   // [512,1024]
  float* out = (float*)d_out;                 // [2,4096,1024] fp32

  char* ws = (char*)d_ws;
  f16* xh     = (f16*)(ws);                   // 16.78 MB  [8192][1024]; reused as Vt after QKV GEMM
  f16* Wqkv_t = (f16*)(ws + 16777216);        //  3.15 MB  [1536][1024]
  f16* Wo_t   = (f16*)(ws + 19922944);        //  1.05 MB  [1024][512]
  f16* Qb     = (f16*)(ws + 20971520);        //  8.39 MB  [16][4096][64]
  f16* Kb     = (f16*)(ws + 29360128);        //  8.39 MB
  f16* Vb     = (f16*)(ws + 37748736);        //  8.39 MB
  f16* At     = (f16*)(ws + 46137344);        //  8.39 MB  [8192][512]
  f16* Vt     = xh;                           //  8.39 MB  [16][64][4096] (xh dead after QKV GEMM)

  convert_x_kernel<<<4096, 256, 0, stream>>>(x, xh, 1048576);

  dim3 tb(64, 8);
  transpose_w_kernel<<<dim3(8, 16), tb, 0, stream>>>(Wq, 512, 0, 1024, Wqkv_t);
  transpose_w_kernel<<<dim3(8, 16), tb, 0, stream>>>(Wkv, 1024, 0, 1024, Wqkv_t + 512 * 1024);
  transpose_w_kernel<<<dim3(8, 16), tb, 0, stream>>>(Wkv, 1024, 512, 1024, Wqkv_t + 1024 * 1024);
  transpose_w_kernel<<<dim3(16, 8), tb, 0, stream>>>(Wo, 1024, 0, 512, Wo_t);

  // fused QKV projection + l2norm (+Q prescale): [8192 x 1536 x 1024]
  gemm_kernel<1><<<768, 256, 0, stream>>>(xh, Wqkv_t, nullptr, Qb, Kb, Vb,
                                          8192, 1536, 1024);
  // V -> V^T (xh space is dead now)
  transpose_v_kernel<<<dim3(64, 16), 256, 0, stream>>>(Vb, Vt, 4096);
  // attention (512 blocks, XCD-decoded inside)
  attn_kernel<<<512, 256, 0, stream>>>(Qb, Kb, Vt, At, 4096);
  // output projection: [8192 x 1024 x 512]
  gemm_kernel<0><<<512, 256, 0, stream>>>(At, Wo_t, out, nullptr, nullptr, nullptr,
                                          8192, 1024, 512);
}

// Round 8
// 155.548 us; speedup vs baseline: 1.2329x; 1.0413x over previous
//
#include <hip/hip_runtime.h>

// ---------------------------------------------------------------------------
// FlashAttention_45844480917693 — cosine-sim attention, MI355X (gfx950)
// R8: attn inner loop software-pipelined — QK MFMAs of sub-tile jt+1 issued
// before softmax VALU of jt (dual-pipe issue within one wave); rsum split
// into 2 accumulators (breaks 32-deep fdot2 chain); 4 transpose_w launches
// merged into 1. Keeps R7's 32x32x16 MFMA, 4 waves x 32 q, KVBLK=128,
// register-resident P via permlane32_swap, XCD-local heads, dbuf K/V.
// ---------------------------------------------------------------------------

typedef _Float16 f16;
typedef _Float16 f16x4 __attribute__((ext_vector_type(4)));
typedef _Float16 f16x8 __attribute__((ext_vector_type(8)));
typedef float f32x4 __attribute__((ext_vector_type(4)));
typedef float f32x16 __attribute__((ext_vector_type(16)));
typedef int i32x4 __attribute__((ext_vector_type(4)));

#define MFMA_F16(a, b, c) __builtin_amdgcn_mfma_f32_16x16x32_f16((a), (b), (c), 0, 0, 0)
#define MFMA32(a, b, c) __builtin_amdgcn_mfma_f32_32x32x16_f16((a), (b), (c), 0, 0, 0)

// 16 * log2(e)
#define QSCALE 23.083120654223414f
// exp2 bias: -QSCALE + 14 (P pre-scaled by 2^14, cancels in rowsum division)
#define EXPBIAS -9.083120654223414f

__device__ __forceinline__ void gl_lds16(const void* g, void* l) {
  // async global->LDS, 16B per lane; LDS dest = wave-uniform base + lane*16
  __builtin_amdgcn_global_load_lds(
      (const __attribute__((address_space(1))) void*)g,
      (__attribute__((address_space(3))) void*)l, 16, 0, 0);
}

// ---------------------------------------------------------------------------
// x (fp32) -> fp16, 8 elements/thread
__global__ void convert_x_kernel(const float* __restrict__ x, f16* __restrict__ xh, int n8) {
  int i = blockIdx.x * 256 + threadIdx.x;
  if (i >= n8) return;
  const float4* xv = (const float4*)x;
  float4 a = xv[2 * i], b = xv[2 * i + 1];
  f16x8 o;
  o[0] = (f16)a.x; o[1] = (f16)a.y; o[2] = (f16)a.z; o[3] = (f16)a.w;
  o[4] = (f16)b.x; o[5] = (f16)b.y; o[6] = (f16)b.z; o[7] = (f16)b.w;
  ((f16x8*)xh)[i] = o;
}

// All weight transposes in one launch. z selects {Wq, Wkv-lo, Wkv-hi, Wo}.
// W [K][ldw] fp32, cols [col0, col0+nc*64) -> out[c][k] fp16 ([out][in])
__global__ void transpose_all_kernel(const float* __restrict__ Wq,
                                     const float* __restrict__ Wkv,
                                     const float* __restrict__ Wo,
                                     f16* __restrict__ Wqkv_t, f16* __restrict__ Wo_t) {
  __shared__ float t[64][65];
  const int z = blockIdx.z;
  const float* W; int ldw, col0, K, nc; f16* out;
  if (z == 0)      { W = Wq;  ldw = 512;  col0 = 0;   K = 1024; nc = 8;  out = Wqkv_t; }
  else if (z == 1) { W = Wkv; ldw = 1024; col0 = 0;   K = 1024; nc = 8;  out = Wqkv_t + 512 * 1024; }
  else if (z == 2) { W = Wkv; ldw = 1024; col0 = 512; K = 1024; nc = 8;  out = Wqkv_t + 1024 * 1024; }
  else             { W = Wo;  ldw = 1024; col0 = 0;   K = 512;  nc = 16; out = Wo_t; }
  if ((int)blockIdx.x >= nc || (int)blockIdx.y >= (K >> 6)) return;
  int tx = threadIdx.x, ty = threadIdx.y;
  int c0 = blockIdx.x * 64, k0 = blockIdx.y * 64;
#pragma unroll
  for (int i = 0; i < 8; i++)
    t[ty + i * 8][tx] = W[(long)(k0 + ty + i * 8) * ldw + col0 + c0 + tx];
  __syncthreads();
#pragma unroll
  for (int i = 0; i < 8; i++)
    out[(long)(c0 + ty + i * 8) * K + k0 + tx] = (f16)t[tx][ty + i * 8];
}

// Vb [bh][n][64] -> Vt [bh][64][n], 64x64 f16 tiles, swizzled LDS
__global__ void transpose_v_kernel(const f16* __restrict__ Vb, f16* __restrict__ Vt, int n) {
  __shared__ f16 t[64 * 64];
  const int tid = threadIdx.x;
  const int bh = blockIdx.y;
  const int n0 = blockIdx.x * 64;
  const f16* src = Vb + ((long)bh * n + n0) * 64;
  const int j = tid >> 3, c = tid & 7;
  f16x8 v0 = *(const f16x8*)(src + j * 64 + c * 8);
  f16x8 v1 = *(const f16x8*)(src + (j + 32) * 64 + c * 8);
  *(f16x8*)(&t[j * 64 + ((c ^ (j & 7)) << 3)]) = v0;
  *(f16x8*)(&t[(j + 32) * 64 + ((c ^ (j & 7)) << 3)]) = v1;  // (j+32)&7 == j&7
  __syncthreads();
  const int d = tid >> 3, cj = tid & 7;
  f16x8 o0, o1;
#pragma unroll
  for (int e = 0; e < 8; e++) {
    int jj = cj * 8 + e;
    o0[e] = t[jj * 64 + (((d >> 3) ^ (jj & 7)) << 3) + (d & 7)];
    o1[e] = t[jj * 64 + ((((d + 32) >> 3) ^ (jj & 7)) << 3) + ((d + 32) & 7)];
  }
  *(f16x8*)(Vt + ((long)bh * 64 + d) * n + n0 + cj * 8) = o0;
  *(f16x8*)(Vt + ((long)bh * 64 + d + 32) * n + n0 + cj * 8) = o1;
}

// ---------------------------------------------------------------------------
// GEMM: C[M][N] = A[M][K] * Bt[N][K]^T, 128x128 tile, BK=32, 4 waves (2x2),
// MODE 0: fp32 C out. MODE 1: fused QKV epilogue (l2norm for Q/K; Q also
// pre-scaled by 16*log2e for the attn exp2 fold).
template <int MODE>
__global__ __launch_bounds__(256, 2)
void gemm_kernel(const f16* __restrict__ A, const f16* __restrict__ Bt,
                 float* __restrict__ C,
                 f16* __restrict__ Qb, f16* __restrict__ Kb, f16* __restrict__ Vb,
                 int M, int N, int K) {
  __shared__ f16 As[128 * 32];
  __shared__ f16 Bs[128 * 32];
  const int tid = threadIdx.x;
  const int lane = tid & 63;
  const int wid = tid >> 6;
  const int wr = wid >> 1, wc = wid & 1;
  const int lr = lane & 15, lk = lane >> 4;
  const int lin = blockIdx.x;
  const int bx = ((lin & 7) << 3) | ((lin >> 3) & 7);  // XCD (lin%8) owns 8 x-panels
  const int by = lin >> 6;
  const long m0 = (long)bx * 128;
  const int n0 = by * 128;

  f32x4 acc[4][4] = {};

  const int c0 = tid, c1 = tid + 256;
  const int ar0 = c0 >> 2, ah0 = (c0 & 3) ^ ((ar0 >> 1) & 3);
  const int ar1 = c1 >> 2, ah1 = (c1 & 3) ^ ((ar1 >> 1) & 3);
  const f16* pa0 = A + (m0 + ar0) * K + ah0 * 8;
  const f16* pa1 = A + (m0 + ar1) * K + ah1 * 8;
  const f16* pb0 = Bt + (long)(n0 + ar0) * K + ah0 * 8;
  const f16* pb1 = Bt + (long)(n0 + ar1) * K + ah1 * 8;

  for (int k0 = 0; k0 < K; k0 += 32) {
    __syncthreads();
    gl_lds16(pa0 + k0, As + c0 * 8);
    gl_lds16(pa1 + k0, As + c1 * 8);
    gl_lds16(pb0 + k0, Bs + c0 * 8);
    gl_lds16(pb1 + k0, Bs + c1 * 8);
    __syncthreads();

    f16x8 af[4], bf[4];
#pragma unroll
    for (int mi = 0; mi < 4; mi++) {
      int row = wr * 64 + mi * 16 + lr;
      int ch = lk ^ ((row >> 1) & 3);
      af[mi] = *(const f16x8*)(As + row * 32 + ch * 8);
    }
#pragma unroll
    for (int ni = 0; ni < 4; ni++) {
      int row = wc * 64 + ni * 16 + lr;
      int ch = lk ^ ((row >> 1) & 3);
      bf[ni] = *(const f16x8*)(Bs + row * 32 + ch * 8);
    }
    __builtin_amdgcn_s_setprio(1);
#pragma unroll
    for (int mi = 0; mi < 4; mi++)
#pragma unroll
      for (int ni = 0; ni < 4; ni++)
        acc[mi][ni] = MFMA_F16(af[mi], bf[ni], acc[mi][ni]);
    __builtin_amdgcn_s_setprio(0);
  }

  if (MODE == 0) {
#pragma unroll
    for (int mi = 0; mi < 4; mi++) {
      long mrow = m0 + wr * 64 + mi * 16 + lk * 4;
#pragma unroll
      for (int r = 0; r < 4; r++)
#pragma unroll
        for (int ni = 0; ni < 4; ni++)
          C[(mrow + r) * N + n0 + wc * 64 + ni * 16 + lr] = acc[mi][ni][r];
    }
  } else {
    const int region = by >> 2;                      // 0=Q, 1=K, 2=V
    const int head = (by & 3) * 2 + wc;
    f16* buf = (region == 0) ? Qb : ((region == 1) ? Kb : Vb);
    const float nscale = (region == 0) ? QSCALE : 1.f;  // Q pre-scaled
#pragma unroll
    for (int mi = 0; mi < 4; mi++) {
      float scl[4];
      if (region < 2) {
#pragma unroll
        for (int r = 0; r < 4; r++) {
          float s2 = 0.f;
#pragma unroll
          for (int ni = 0; ni < 4; ni++) s2 += acc[mi][ni][r] * acc[mi][ni][r];
          s2 += __shfl_xor(s2, 1);
          s2 += __shfl_xor(s2, 2);
          s2 += __shfl_xor(s2, 4);
          s2 += __shfl_xor(s2, 8);
          scl[r] = nscale / fmaxf(sqrtf(s2), 1e-12f);
        }
      } else {
#pragma unroll
        for (int r = 0; r < 4; r++) scl[r] = 1.f;
      }
#pragma unroll
      for (int r = 0; r < 4; r++) {
        int m = (int)m0 + wr * 64 + mi * 16 + lk * 4 + r;
        int bb = m >> 12, nn = m & 4095;
        f16* dst = buf + (((long)(bb * 8 + head) * 4096 + nn) << 6);
#pragma unroll
        for (int ni = 0; ni < 4; ni++)
          dst[ni * 16 + lr] = (f16)(acc[mi][ni][r] * scl[r]);
      }
    }
  }
}

// ---------------------------------------------------------------------------
// Attention v7: 32x32x16 MFMA, 4 waves x 32 q, KVBLK=128, software-pipelined
// sub-tiles: QK(jt+1) MFMAs issued before softmax(jt) VALU so the scheduler
// can dual-issue MFMA + VALU within one wave. P register-resident via
// permlane32_swap; rowsum via 2 independent fdot2 chains.
__global__ __launch_bounds__(256, 2)
void attn_kernel(const f16* __restrict__ Qb, const f16* __restrict__ Kb,
                 const f16* __restrict__ Vt, f16* __restrict__ Ob, int n) {
  __shared__ f16 Ks[2][128 * 64];    // [j][d], 16B-chunk ^= (j&7)   16KB x2
  __shared__ f16 Vs[2][64 * 128];    // [d][j], 16B-chunk ^= (d&15)  16KB x2
  const int tid = threadIdx.x, lane = tid & 63, wid = tid >> 6;  // wid 0..3
  const int ql = lane & 31, hi = lane >> 5;
  const int lin = blockIdx.x;
  const int bh = (lin & 7) | ((lin >> 8) << 3);
  const int qx = (lin >> 3) & 31;
  const long nl = n;
  const f16* Qg = Qb + (long)bh * nl * 64;
  const f16* Kg = Kb + (long)bh * nl * 64;
  const f16* Vg = Vt + (long)bh * 64 * nl;
  const int q0w = qx * 128 + wid * 32;

  // Q fragments (B-operand): col q = ql, k d = kc*16 + hi*8 + e
  f16x8 qf[4];
#pragma unroll
  for (int kc = 0; kc < 4; kc++)
    qf[kc] = *(const f16x8*)(Qg + (long)(q0w + ql) * 64 + kc * 16 + hi * 8);

  // staging source offsets (4 K-chunks + 4 V-chunks per thread per tile);
  // LDS dest stays lane-linear, source pre-swizzled.
  int ksrc[4], vsrc[4];
#pragma unroll
  for (int p = 0; p < 4; p++) {
    const int ci = tid + p * 256;
    const int kj = ci >> 3, kc_ = ci & 7;
    ksrc[p] = kj * 64 + ((kc_ ^ (kj & 7)) << 3);
    const int vd = ci >> 4, vc = ci & 15;
    vsrc[p] = vd * n + ((vc ^ (vd & 15)) << 3);
  }

  f32x16 oacc[2][2] = {};   // [kl][dt] — 4 independent MFMA chains
  float rsum0 = 0.f, rsum1 = 0.f;
  f32x16 initv;
#pragma unroll
  for (int e = 0; e < 16; e++) initv[e] = EXPBIAS;
  const auto one2 = __builtin_amdgcn_cvt_pkrtz(1.f, 1.f);

  // prologue: stage tile 0 into buf 0
#pragma unroll
  for (int p = 0; p < 4; p++) {
    gl_lds16(Kg + ksrc[p], &Ks[0][(tid + p * 256) * 8]);
    gl_lds16(Vg + vsrc[p], &Vs[0][(tid + p * 256) * 8]);
  }
  __syncthreads();

  const int nt = n >> 7;
  for (int t = 0; t < nt; t++) {
    const int cur = t & 1;
    if (t + 1 < nt) {
      const long kadv = (long)(t + 1) * 8192;   // 128 rows * 64 d
      const long vadv = (long)(t + 1) * 128;    // +128 j
#pragma unroll
      for (int p = 0; p < 4; p++) {
        gl_lds16(Kg + kadv + ksrc[p], &Ks[cur ^ 1][(tid + p * 256) * 8]);
        gl_lds16(Vg + vadv + vsrc[p], &Vs[cur ^ 1][(tid + p * 256) * 8]);
      }
    }

    // ---- software pipeline over 32-j sub-tiles ----
    f32x16 s_cur, s_nxt;
    {  // QK(jt=0)
      const int j = ql, sw = j & 7;
      __builtin_amdgcn_s_setprio(1);
      const f16x8 k0 = *(const f16x8*)(&Ks[cur][j * 64 + ((hi ^ sw) << 3)]);
      s_cur = MFMA32(k0, qf[0], initv);
#pragma unroll
      for (int kc = 1; kc < 4; kc++) {
        const f16x8 kf = *(const f16x8*)(&Ks[cur][j * 64 + ((((kc << 1) | hi) ^ sw) << 3)]);
        s_cur = MFMA32(kf, qf[kc], s_cur);
      }
      __builtin_amdgcn_s_setprio(0);
    }

#pragma unroll
    for (int jt = 0; jt < 4; jt++) {
      // issue QK(jt+1) — overlaps the softmax VALU below
      if (jt < 3) {
        const int j = (jt + 1) * 32 + ql, sw = j & 7;
        const f16x8 k0 = *(const f16x8*)(&Ks[cur][j * 64 + ((hi ^ sw) << 3)]);
        s_nxt = MFMA32(k0, qf[0], initv);
#pragma unroll
        for (int kc = 1; kc < 4; kc++) {
          const f16x8 kf = *(const f16x8*)(&Ks[cur][j * 64 + ((((kc << 1) | hi) ^ sw) << 3)]);
          s_nxt = MFMA32(kf, qf[kc], s_nxt);
        }
      }

      // softmax on s_cur: exp2 -> pack -> fdot2 rowsum (2 chains)
      int w[8];
#pragma unroll
      for (int m = 0; m < 8; m++) {
        const float pa = __builtin_amdgcn_exp2f(s_cur[2 * m]);
        const float pb = __builtin_amdgcn_exp2f(s_cur[2 * m + 1]);
        const auto h = __builtin_amdgcn_cvt_pkrtz(pa, pb);
        if (m & 1)
          rsum1 = __builtin_amdgcn_fdot2(h, one2, rsum1, false);
        else
          rsum0 = __builtin_amdgcn_fdot2(h, one2, rsum0, false);
        w[m] = __builtin_bit_cast(int, h);
      }
#pragma unroll
      for (int kl = 0; kl < 2; kl++) {
        int a0 = w[4 * kl + 0], a1 = w[4 * kl + 1];
        int a2 = w[4 * kl + 2], a3 = w[4 * kl + 3];
        // v_permlane32_swap: dst.hi32lanes <-> src.lo32lanes
        asm volatile("v_permlane32_swap_b32 %0, %1" : "+v"(a0), "+v"(a2));
        asm volatile("v_permlane32_swap_b32 %0, %1" : "+v"(a1), "+v"(a3));
        i32x4 fi = {a0, a1, a2, a3};
        const f16x8 pfrag = __builtin_bit_cast(f16x8, fi);
        const int kb = jt * 2 + kl;
        __builtin_amdgcn_s_setprio(1);
#pragma unroll
        for (int dt = 0; dt < 2; dt++) {
          const int d = dt * 32 + ql;
          const f16x8 vf =
              *(const f16x8*)(&Vs[cur][d * 128 + ((((kb << 1) | hi) ^ (d & 15)) << 3)]);
          oacc[kl][dt] = MFMA32(pfrag, vf, oacc[kl][dt]);
        }
        __builtin_amdgcn_s_setprio(0);
      }
      if (jt < 3) s_cur = s_nxt;
    }

    __syncthreads();  // drains prefetch vmcnt + all waves done with buf[cur]
  }

  // final rowsum (other hi-half holds complementary j's), divide, store
  float rsum = rsum0 + rsum1;
  rsum += __shfl_xor(rsum, 32);
  const int bb = bh >> 3, hh = bh & 7;
#pragma unroll
  for (int r = 0; r < 16; r++) {
    const int qloc = (r & 3) + 8 * (r >> 2) + 4 * hi;
    const float sm = __shfl(rsum, qloc);                // rowsum for q0w+qloc
    const float inv = 1.f / fmaxf(sm, 0.016384f);       // 1e-6 * 2^14
    f16* dst = Ob + (((long)(bb * 4096 + q0w + qloc)) << 9) + hh * 64;
    dst[ql] = (f16)((oacc[0][0][r] + oacc[1][0][r]) * inv);
    dst[32 + ql] = (f16)((oacc[0][1][r] + oacc[1][1][r]) * inv);
  }
}

// ---------------------------------------------------------------------------
extern "C" void kernel_launch(void* const* d_in, const int* in_sizes, int n_in,
                              void* d_out, int out_size, void* d_ws, size_t ws_size,
                              hipStream_t stream) {
  const float* x   = (const float*)d_in[0];   // [2,4096,1024]
  const float* Wq  = (const float*)d_in[1];   // [1024,512]
  const float* Wkv = (const float*)d_in[2];   // [1024,1024]
  const float* Wo  = (const float*)d_in[3];   // [512,1024]
  float* out = (float*)d_out;                 // [2,4096,1024] fp32

  char* ws = (char*)d_ws;
  f16* xh     = (f16*)(ws);                   // 16.78 MB  [8192][1024]; reused as Vt after QKV GEMM
  f16* Wqkv_t = (f16*)(ws + 16777216);        //  3.15 MB  [1536][1024]
  f16* Wo_t   = (f16*)(ws + 19922944);        //  1.05 MB  [1024][512]
  f16* Qb     = (f16*)(ws + 20971520);        //  8.39 MB  [16][4096][64]
  f16* Kb     = (f16*)(ws + 29360128);        //  8.39 MB
  f16* Vb     = (f16*)(ws + 37748736);        //  8.39 MB
  f16* At     = (f16*)(ws + 46137344);        //  8.39 MB  [8192][512]
  f16* Vt     = xh;                           //  8.39 MB  [16][64][4096] (xh dead after QKV GEMM)

  convert_x_kernel<<<4096, 256, 0, stream>>>(x, xh, 1048576);

  // all weight transposes in one launch
  transpose_all_kernel<<<dim3(16, 16, 4), dim3(64, 8), 0, stream>>>(Wq, Wkv, Wo, Wqkv_t, Wo_t);

  // fused QKV projection + l2norm (+Q prescale): [8192 x 1536 x 1024]
  gemm_kernel<1><<<768, 256, 0, stream>>>(xh, Wqkv_t, nullptr, Qb, Kb, Vb,
                                          8192, 1536, 1024);
  // V -> V^T (xh space is dead now)
  transpose_v_kernel<<<dim3(64, 16), 256, 0, stream>>>(Vb, Vt, 4096);
  // attention (512 blocks, XCD-decoded inside)
  attn_kernel<<<512, 256, 0, stream>>>(Qb, Kb, Vt, At, 4096);
  // output projection: [8192 x 1024 x 512]
  gemm_kernel<0><<<512, 256, 0, stream>>>(At, Wo_t, out, nullptr, nullptr, nullptr,
                                          8192, 1024, 512);
}